// Round 3
// baseline (670.969 us; speedup 1.0000x reference)
//
#include <hip/hip_runtime.h>
#include <hip/hip_bf16.h>
#include <math.h>

typedef unsigned long long u64;
typedef unsigned int u32;
typedef __hip_bfloat16 bf16;

#define N 1024
#define NCLS 21
#define APP 1024
#define DF 128
#define NH 16
#define DK 64

__device__ __forceinline__ float b2f(bf16 x) { return __bfloat162float(x); }

// ---------------------------------------------------------------- k_prep
// per-roi: softmax -> prob (f32 expf + sequential sum to mimic np), first-max
// argmax, bbox decode with reference's parity clamp, composite sort key.
__global__ void k_prep(const float* __restrict__ roi, const float* __restrict__ cls_loc,
                       const float* __restrict__ score, const int* __restrict__ size,
                       float* __restrict__ prob, int* __restrict__ label,
                       float* __restrict__ bbox, u64* __restrict__ keys)
{
    int i = blockIdx.x * 256 + threadIdx.x;
    if (i >= N) return;
    float s[NCLS];
    float mx = -1e30f; int am = 0;
    for (int c = 0; c < NCLS; c++) {
        s[c] = score[i * NCLS + c];
        if (s[c] > mx) { mx = s[c]; am = c; }
    }
    float sum = 0.f;
    for (int c = 0; c < NCLS; c++) sum += expf(s[c] - mx);   // strict l-to-r f32
    float p = 1.0f / sum;   // == max of softmax row (exp(0)=1 numerator)

    float y0 = roi[i*4+0], x0 = roi[i*4+1];
    float y1 = roi[i*4+2], x1 = roi[i*4+3];
    float hh = y1 - y0, ww = x1 - x0;
    float cy = y0 + 0.5f * hh, cx = x0 + 0.5f * ww;
    float l0 = cls_loc[i*84 + am*4 + 0] * 0.1f;
    float l1 = cls_loc[i*84 + am*4 + 1] * 0.1f;
    float l2 = cls_loc[i*84 + am*4 + 2] * 0.2f;
    float l3 = cls_loc[i*84 + am*4 + 3] * 0.2f;
    float ncy = l0 * hh + cy, ncx = l1 * ww + cx;
    float nh = expf(l2) * hh, nw = expf(l3) * ww;
    float b0 = ncy - 0.5f * nh, b1 = ncx - 0.5f * nw;
    float b2v = ncy + 0.5f * nh, b3 = ncx + 0.5f * nw;
    // reference clamps [N,21,4] view at [:,0::2]->size[0], [:,1::2]->size[1]
    float lim = ((am & 1) == 0) ? (float)size[0] : (float)size[1];
    b0  = fminf(fmaxf(b0, 0.f), lim);
    b1  = fminf(fmaxf(b1, 0.f), lim);
    b2v = fminf(fmaxf(b2v, 0.f), lim);
    b3  = fminf(fmaxf(b3, 0.f), lim);
    prob[i] = p; label[i] = am;
    bbox[i*4+0] = b0; bbox[i*4+1] = b1; bbox[i*4+2] = b2v; bbox[i*4+3] = b3;
    // p>0 -> IEEE bits monotone; invert for descending, low bits = index (stable)
    keys[i] = ((u64)(0xFFFFFFFFu - __float_as_uint(p)) << 32) | (u32)i;
}

// ---------------------------------------------------------------- k_sort
// single-block bitonic sort; writes f32 outputs: labels (out[N..2N)), bbox (out[2N..6N))
__global__ void __launch_bounds__(1024) k_sort(
        const u64* __restrict__ keys, const float* __restrict__ prob,
        const int* __restrict__ label, const float* __restrict__ bbox,
        int* __restrict__ order, float* __restrict__ sprob,
        float* __restrict__ sbbox, float* __restrict__ out)
{
    __shared__ u64 sk[N];
    int t = threadIdx.x;
    sk[t] = keys[t];
    __syncthreads();
    for (int k = 2; k <= N; k <<= 1) {
        for (int j = k >> 1; j > 0; j >>= 1) {
            int p = t ^ j;
            if (p > t) {
                u64 a = sk[t], b = sk[p];
                bool up = ((t & k) == 0);
                if ((a > b) == up) { sk[t] = b; sk[p] = a; }
            }
            __syncthreads();
        }
    }
    int o = (int)(sk[t] & 0xFFFFFFFFull);
    order[t] = o;
    sprob[t] = prob[o];
    float b0 = bbox[o*4+0], b1 = bbox[o*4+1], b2 = bbox[o*4+2], b3 = bbox[o*4+3];
    sbbox[t*4+0] = b0; sbbox[t*4+1] = b1; sbbox[t*4+2] = b2; sbbox[t*4+3] = b3;
    out[N + t] = (float)(label[o] - 1);
    out[2*N + t*4 + 0] = b0;
    out[2*N + t*4 + 1] = b1;
    out[2*N + t*4 + 2] = b2;
    out[2*N + t*4 + 3] = b3;
}

// ---------------------------------------------------------------- k_emb
// emb[i,j] = sorted_feats[i,:]@feat_w[:,j] + feat_b[j] + rank_emb(i,:)@rank_w[:,j] + rank_b[j]
__global__ void k_emb(const int* __restrict__ order, const float* __restrict__ app,
                      const float* __restrict__ feat_w, const float* __restrict__ feat_b,
                      const float* __restrict__ rank_w, const float* __restrict__ rank_b,
                      float* __restrict__ emb)
{
    __shared__ float af[APP];
    __shared__ float rk[APP];
    int i = blockIdx.x, t = threadIdx.x;   // 128 threads
    int o = order[i];
    for (int d = t; d < APP; d += 128) af[d] = app[o * APP + d];
    float fi = (float)i;
    for (int d = t; d < APP/2; d += 128) {
        float dm = exp2f(-(float)d * 0.019464422f);   // 1000^(-d/512)
        float mul = fi * dm;
        rk[d]       = __sinf(mul);
        rk[512 + d] = __cosf(mul);
    }
    __syncthreads();
    float acc = feat_b[t] + rank_b[t];
    for (int d = 0; d < APP; d++)
        acc += af[d] * feat_w[d*DF + t] + rk[d] * rank_w[d*DF + t];
    emb[i * DF + t] = acc;
}

// ---------------------------------------------------------------- k_qkv
// q/k/v[h,n,kk] = emb[n,:]@W[h,:,kk] + b[h,kk]  (bf16 staging outputs)
__global__ void k_qkv(const float* __restrict__ emb,
                      const float* __restrict__ wq, const float* __restrict__ bq,
                      const float* __restrict__ wk, const float* __restrict__ bk,
                      const float* __restrict__ wv, const float* __restrict__ bv,
                      bf16* __restrict__ q, bf16* __restrict__ k, bf16* __restrict__ v)
{
    __shared__ float et[64][DF];
    int h = blockIdx.x, nt = blockIdx.y, t = threadIdx.x;
    int n0 = nt * 64;
    for (int idx = t; idx < 64 * DF; idx += 256) {
        int r = idx >> 7, c = idx & 127;
        et[r][c] = emb[(n0 + r) * DF + c];
    }
    __syncthreads();
    int kk = t & 63, g = t >> 6;
    const float* Ws[3] = { wq, wk, wv };
    const float* Bs[3] = { bq, bk, bv };
    bf16* Os[3] = { q, k, v };
    for (int m3 = 0; m3 < 3; m3++) {
        float bias = Bs[m3][h * DK + kk];
        float acc[16];
        #pragma unroll
        for (int ii = 0; ii < 16; ii++) acc[ii] = bias;
        for (int d = 0; d < DF; d++) {
            float w = Ws[m3][(h * DF + d) * DK + kk];
            #pragma unroll
            for (int ii = 0; ii < 16; ii++) acc[ii] += et[g*16 + ii][d] * w;
        }
        for (int ii = 0; ii < 16; ii++)
            Os[m3][((size_t)h * N + n0 + g*16 + ii) * DK + kk] = __float2bfloat16(acc[ii]);
    }
}

// ---------------------------------------------------------------- k_scores
// L[g,m,n] = (k[h0+g,m,:].q[h0+g,n,:])/8, stored bf16
__global__ void k_scores(const bf16* __restrict__ kmat, const bf16* __restrict__ qmat,
                         bf16* __restrict__ L, int h0)
{
    __shared__ float kt[64][65];
    __shared__ float qt[64][65];
    int g = blockIdx.z, h = h0 + g;
    int mt = blockIdx.y, nt = blockIdx.x, t = threadIdx.x;
    for (int idx = t; idx < 4096; idx += 256) {
        int r = idx >> 6, c = idx & 63;
        kt[r][c] = b2f(kmat[((size_t)h * N + mt*64 + r) * DK + c]);
        qt[r][c] = b2f(qmat[((size_t)h * N + nt*64 + r) * DK + c]);
    }
    __syncthreads();
    int tm = t >> 4, tn = t & 15;
    float acc[4][4] = {};
    for (int kk = 0; kk < DK; kk++) {
        float a[4], b[4];
        #pragma unroll
        for (int i2 = 0; i2 < 4; i2++) { a[i2] = kt[tm*4 + i2][kk]; b[i2] = qt[tn*4 + i2][kk]; }
        #pragma unroll
        for (int i2 = 0; i2 < 4; i2++)
            #pragma unroll
            for (int j2 = 0; j2 < 4; j2++) acc[i2][j2] += a[i2] * b[j2];
    }
    for (int i2 = 0; i2 < 4; i2++)
        for (int j2 = 0; j2 < 4; j2++) {
            int m = mt*64 + tm*4 + i2, n = nt*64 + tn*4 + j2;
            L[((size_t)g << 20) + ((size_t)m << 10) + n] = __float2bfloat16(acc[i2][j2] * 0.125f);
        }
}

// ---------------------------------------------------------------- k_logwg
// L[g,m,n] += log(max(relu(pos_emb(m,n).wg_w[h0+g] + wg_b[h0+g]), 1e-6))
// pos_emb computed ONCE per (m,n) per launch, shared across the G heads.
__global__ void k_logwg(const float* __restrict__ sbbox, const float* __restrict__ wgw,
                        const float* __restrict__ wgb, bf16* __restrict__ L,
                        int h0, int G)
{
    __shared__ float sw[NH][DK];
    __shared__ float sb[NH];
    __shared__ float mbb[4];   // cx_m, cy_m, w_m, h_m
    int m = blockIdx.x, nc = blockIdx.y, t = threadIdx.x;
    for (int idx = t; idx < NH * DK; idx += 256) sw[idx >> 6][idx & 63] = wgw[idx];
    if (t < NH) sb[t] = wgb[t];
    if (t == 0) {
        float b0 = sbbox[m*4+0], b1 = sbbox[m*4+1], b2 = sbbox[m*4+2], b3 = sbbox[m*4+3];
        mbb[0] = (b0 + b2) * 0.5f; mbb[1] = (b1 + b3) * 0.5f;
        mbb[2] = b2 - b0 + 1.0f;   mbb[3] = b3 - b1 + 1.0f;
    }
    __syncthreads();
    int n = nc * 256 + t;
    float b0 = sbbox[n*4+0], b1 = sbbox[n*4+1], b2 = sbbox[n*4+2], b3 = sbbox[n*4+3];
    float cxn = (b0 + b2) * 0.5f, cyn = (b1 + b3) * 0.5f;
    float wn = b2 - b0 + 1.0f, hn = b3 - b1 + 1.0f;
    float dx = __logf(fmaxf(fabsf((mbb[0] - cxn) / mbb[2]), 1e-3f));
    float dy = __logf(fmaxf(fabsf((mbb[1] - cyn) / mbb[3]), 1e-3f));
    float dw = __logf(mbb[2] / wn);
    float dh = __logf(mbb[3] / hn);
    float pos[4] = { dx, dy, dw, dh };
    const float dmt[8] = { 1.0f, 0.42169650342f, 0.177827941f, 0.0749894209f,
                           0.0316227766f, 0.01333521432f, 0.00562341325f, 0.00237137371f };
    float emb[64];
    #pragma unroll
    for (int c = 0; c < 4; c++)
        #pragma unroll
        for (int f = 0; f < 8; f++) {
            float arg = 100.0f * pos[c] * dmt[f];   // |arg| <= ~700 rad, within v_sin range
            emb[c*8 + f]      = __sinf(arg);
            emb[32 + c*8 + f] = __cosf(arg);
        }
    size_t base = ((size_t)m << 10) + n;
    for (int g = 0; g < G; g++) {
        int hh = h0 + g;
        float wg = sb[hh];
        #pragma unroll
        for (int e = 0; e < 64; e++) wg += emb[e] * sw[hh][e];
        wg = fmaxf(wg, 0.f);
        float lw = __logf(fmaxf(wg, 1e-6f));
        size_t idx = ((size_t)g << 20) + base;
        L[idx] = __float2bfloat16(b2f(L[idx]) + lw);
    }
}

// ---------------------------------------------------------------- k_soft
// per (g, 4 rows): softmax over n of L, then rel[h0+g,m,:] = sum_n w*v[h0+g,n,:]
__global__ void k_soft(const bf16* __restrict__ L, const bf16* __restrict__ v,
                       bf16* __restrict__ rel, int h0)
{
    __shared__ float wl[4][256];
    __shared__ float smx[4], sden[4];
    int g = blockIdx.x, h = h0 + g, mg = blockIdx.y, t = threadIdx.x;
    int r = t >> 6, l = t & 63;
    int m = mg * 4 + r;
    size_t rowbase = ((size_t)g << 20) + ((size_t)m << 10);
    float mx = -1e30f, sum = 0.f;
    for (int it = 0; it < 16; it++) {
        float x = b2f(L[rowbase + l + it*64]);
        if (x > mx) { sum = sum * __expf(mx - x) + 1.0f; mx = x; }
        else        { sum += __expf(x - mx); }
    }
    #pragma unroll
    for (int off = 1; off < 64; off <<= 1) {
        float omx = __shfl_xor(mx, off, 64);
        float osum = __shfl_xor(sum, off, 64);
        float nm = fmaxf(mx, omx);
        sum = sum * __expf(mx - nm) + osum * __expf(omx - nm);
        mx = nm;
    }
    if (l == 0) { smx[r] = mx; sden[r] = 1.0f / sum; }
    __syncthreads();
    int kk = t & 63, rr = t >> 6;
    float acc = 0.f;
    for (int nt = 0; nt < N; nt += 256) {
        __syncthreads();
        #pragma unroll
        for (int c2 = 0; c2 < 4; c2++) {
            int nn = (t & 63) + c2 * 64;
            float x = b2f(L[((size_t)g << 20) + ((size_t)(mg*4 + rr) << 10) + nt + nn]);
            wl[rr][nn] = __expf(x - smx[rr]) * sden[rr];
        }
        __syncthreads();
        for (int nn = 0; nn < 256; nn++)
            acc += wl[rr][nn] * b2f(v[((size_t)h * N + nt + nn) * DK + kk]);
    }
    rel[((size_t)h * N + m) * DK + kk] = __float2bfloat16(acc);
}

// ---------------------------------------------------------------- k_final
// out[m] (f32) = sigmoid((rel[:,m,:]+feats).logit_w + b) * sorted_prob[m]
__global__ void k_final(const bf16* __restrict__ rel, const int* __restrict__ order,
                        const float* __restrict__ app, const float* __restrict__ lw,
                        const float* __restrict__ lb, const float* __restrict__ sprob,
                        float* __restrict__ out)
{
    __shared__ float red[2];
    int m = blockIdx.x, t = threadIdx.x;   // 128 threads
    int o = order[m];
    float s = 0.f;
    for (int j = t; j < APP; j += 128) {
        int hh = j >> 6, kk = j & 63;
        float rv = b2f(rel[((size_t)hh * N + m) * DK + kk]) + app[o * APP + j];
        s += rv * lw[j];
    }
    #pragma unroll
    for (int off = 32; off > 0; off >>= 1) s += __shfl_down(s, off, 64);
    if ((t & 63) == 0) red[t >> 6] = s;
    __syncthreads();
    if (t == 0) {
        float tot = red[0] + red[1] + lb[0];
        float s1 = 1.0f / (1.0f + expf(-tot));
        out[m] = s1 * sprob[m];
    }
}

// ---------------------------------------------------------------- launch
extern "C" void kernel_launch(void* const* d_in, const int* in_sizes, int n_in,
                              void* d_out, int out_size, void* d_ws, size_t ws_size,
                              hipStream_t stream)
{
    const float* roi      = (const float*)d_in[0];
    const float* cls_loc  = (const float*)d_in[1];
    const float* score    = (const float*)d_in[2];
    const float* app      = (const float*)d_in[3];
    const int*   size     = (const int*)d_in[4];
    const float* rank_w   = (const float*)d_in[5];
    const float* rank_b   = (const float*)d_in[6];
    const float* feat_w   = (const float*)d_in[7];
    const float* feat_b   = (const float*)d_in[8];
    const float* logit_w  = (const float*)d_in[9];
    const float* logit_b  = (const float*)d_in[10];
    const float* wg_w     = (const float*)d_in[11];
    const float* wg_b     = (const float*)d_in[12];
    const float* wk_w     = (const float*)d_in[13];
    const float* wk_b     = (const float*)d_in[14];
    const float* wq_w     = (const float*)d_in[15];
    const float* wq_b     = (const float*)d_in[16];
    const float* wv_w     = (const float*)d_in[17];
    const float* wv_b     = (const float*)d_in[18];
    float* out = (float*)d_out;   // f32: [scores 1024 | labels 1024 | bbox 4096]

    // workspace layout (byte offsets)
    char* ws = (char*)d_ws;
    float* prob  = (float*)(ws + 0);          // 4 KB
    int*   label = (int*)  (ws + 4096);       // 4 KB
    float* bbox  = (float*)(ws + 8192);       // 16 KB
    u64*   keys  = (u64*)  (ws + 24576);      // 8 KB
    int*   order = (int*)  (ws + 32768);      // 4 KB
    float* sprob = (float*)(ws + 36864);      // 4 KB
    float* sbbox = (float*)(ws + 40960);      // 16 KB
    float* emb   = (float*)(ws + 57344);      // 512 KB
    bf16*  q     = (bf16*) (ws + 581632);     // 2 MB
    bf16*  k     = (bf16*) (ws + 2678784);    // 2 MB
    bf16*  v     = (bf16*) (ws + 4775936);    // 2 MB
    bf16*  rel   = (bf16*) (ws + 6873088);    // 2 MB
    bf16*  L     = (bf16*) (ws + 8970240);    // G * 2 MB

    // pick head-group size G so the layout fits ws_size (host-side, capture-safe)
    size_t fixed = 8970240;
    int G = 1;
    for (int g2 = 16; g2 >= 1; g2 >>= 1)
        if (fixed + (size_t)g2 * 2097152 <= ws_size) { G = g2; break; }

    k_prep<<<4, 256, 0, stream>>>(roi, cls_loc, score, size, prob, label, bbox, keys);
    k_sort<<<1, 1024, 0, stream>>>(keys, prob, label, bbox, order, sprob, sbbox, out);
    k_emb<<<1024, 128, 0, stream>>>(order, app, feat_w, feat_b, rank_w, rank_b, emb);
    k_qkv<<<dim3(16, 16), 256, 0, stream>>>(emb, wq_w, wq_b, wk_w, wk_b, wv_w, wv_b, q, k, v);
    for (int h0 = 0; h0 < NH; h0 += G) {
        k_scores<<<dim3(16, 16, G), 256, 0, stream>>>(k, q, L, h0);
        k_logwg<<<dim3(1024, 4), 256, 0, stream>>>(sbbox, wg_w, wg_b, L, h0, G);
        k_soft<<<dim3(G, 256), 256, 0, stream>>>(L, v, rel, h0);
    }
    k_final<<<1024, 128, 0, stream>>>(rel, order, app, logit_w, logit_b, sprob, out);
}

// Round 4
// 613.672 us; speedup vs baseline: 1.0934x; 1.0934x over previous
//
#include <hip/hip_runtime.h>
#include <hip/hip_bf16.h>
#include <math.h>

typedef unsigned long long u64;
typedef unsigned int u32;
typedef __hip_bfloat16 bf16;

#define N 1024
#define NCLS 21
#define APP 1024
#define DF 128
#define NH 16
#define DK 64

#define HG 4     // heads per k_attn block
#define TM 16    // m rows per k_attn block
#define TN 32    // n tile width

__device__ __forceinline__ float b2f(bf16 x) { return __bfloat162float(x); }

// ---------------------------------------------------------------- k_prep
__global__ void k_prep(const float* __restrict__ roi, const float* __restrict__ cls_loc,
                       const float* __restrict__ score, const int* __restrict__ size,
                       float* __restrict__ prob, int* __restrict__ label,
                       float* __restrict__ bbox, u64* __restrict__ keys)
{
    int i = blockIdx.x * 256 + threadIdx.x;
    if (i >= N) return;
    float s[NCLS];
    float mx = -1e30f; int am = 0;
    for (int c = 0; c < NCLS; c++) {
        s[c] = score[i * NCLS + c];
        if (s[c] > mx) { mx = s[c]; am = c; }
    }
    float sum = 0.f;
    for (int c = 0; c < NCLS; c++) sum += expf(s[c] - mx);
    float p = 1.0f / sum;

    float y0 = roi[i*4+0], x0 = roi[i*4+1];
    float y1 = roi[i*4+2], x1 = roi[i*4+3];
    float hh = y1 - y0, ww = x1 - x0;
    float cy = y0 + 0.5f * hh, cx = x0 + 0.5f * ww;
    float l0 = cls_loc[i*84 + am*4 + 0] * 0.1f;
    float l1 = cls_loc[i*84 + am*4 + 1] * 0.1f;
    float l2 = cls_loc[i*84 + am*4 + 2] * 0.2f;
    float l3 = cls_loc[i*84 + am*4 + 3] * 0.2f;
    float ncy = l0 * hh + cy, ncx = l1 * ww + cx;
    float nh = expf(l2) * hh, nw = expf(l3) * ww;
    float b0 = ncy - 0.5f * nh, b1 = ncx - 0.5f * nw;
    float b2v = ncy + 0.5f * nh, b3 = ncx + 0.5f * nw;
    float lim = ((am & 1) == 0) ? (float)size[0] : (float)size[1];
    b0  = fminf(fmaxf(b0, 0.f), lim);
    b1  = fminf(fmaxf(b1, 0.f), lim);
    b2v = fminf(fmaxf(b2v, 0.f), lim);
    b3  = fminf(fmaxf(b3, 0.f), lim);
    prob[i] = p; label[i] = am;
    bbox[i*4+0] = b0; bbox[i*4+1] = b1; bbox[i*4+2] = b2v; bbox[i*4+3] = b3;
    keys[i] = ((u64)(0xFFFFFFFFu - __float_as_uint(p)) << 32) | (u32)i;
}

// ---------------------------------------------------------------- k_sort
__global__ void __launch_bounds__(1024) k_sort(
        const u64* __restrict__ keys, const float* __restrict__ prob,
        const int* __restrict__ label, const float* __restrict__ bbox,
        int* __restrict__ order, float* __restrict__ sprob,
        float* __restrict__ sbbox, float* __restrict__ out)
{
    __shared__ u64 sk[N];
    int t = threadIdx.x;
    sk[t] = keys[t];
    __syncthreads();
    for (int k = 2; k <= N; k <<= 1) {
        for (int j = k >> 1; j > 0; j >>= 1) {
            int p = t ^ j;
            if (p > t) {
                u64 a = sk[t], b = sk[p];
                bool up = ((t & k) == 0);
                if ((a > b) == up) { sk[t] = b; sk[p] = a; }
            }
            __syncthreads();
        }
    }
    int o = (int)(sk[t] & 0xFFFFFFFFull);
    order[t] = o;
    sprob[t] = prob[o];
    float b0 = bbox[o*4+0], b1 = bbox[o*4+1], b2 = bbox[o*4+2], b3 = bbox[o*4+3];
    sbbox[t*4+0] = b0; sbbox[t*4+1] = b1; sbbox[t*4+2] = b2; sbbox[t*4+3] = b3;
    out[N + t] = (float)(label[o] - 1);
    out[2*N + t*4 + 0] = b0;
    out[2*N + t*4 + 1] = b1;
    out[2*N + t*4 + 2] = b2;
    out[2*N + t*4 + 3] = b3;
}

// ---------------------------------------------------------------- k_emb (split-K partials)
// part[dc][row][col] = sorted_app[row, dc*64..+64] @ feat_w[dc*64.., col]
//                    + rank[row, dc*64..+64] @ rank_w[dc*64.., col]
__global__ void __launch_bounds__(256) k_emb(
        const int* __restrict__ order, const float* __restrict__ app,
        const float* __restrict__ feat_w, const float* __restrict__ rank_w,
        float* __restrict__ part)
{
    __shared__ float sAT[64][68];    // [d][row], padded
    __shared__ float sW[64][128];    // [d][col]
    __shared__ int sOrd[64];
    int rt = blockIdx.x, dc = blockIdx.y, t = threadIdx.x;
    int r0 = rt * 64, d0 = dc * 64;
    if (t < 64) sOrd[t] = order[r0 + t];
    __syncthreads();
    // ---- phase 1: appearance part
    for (int i = 0; i < 32; i++) {               // 64x128 W
        int idx = t + i * 256;
        sW[idx >> 7][idx & 127] = feat_w[(size_t)(d0 + (idx >> 7)) * 128 + (idx & 127)];
    }
    for (int i = 0; i < 16; i++) {               // 64x64 A^T
        int idx = t + i * 256;
        int r = idx >> 6, d = idx & 63;
        sAT[d][r] = app[(size_t)sOrd[r] * 1024 + d0 + d];
    }
    __syncthreads();
    int tr = t >> 4, tc = t & 15;                // 16x4 rows, 16x8 cols
    float acc[4][8];
    #pragma unroll
    for (int i = 0; i < 4; i++)
        #pragma unroll
        for (int j = 0; j < 8; j++) acc[i][j] = 0.f;
    for (int d = 0; d < 64; d++) {
        float4 a4 = *(float4*)&sAT[d][tr*4];
        float4 w0 = *(float4*)&sW[d][tc*8];
        float4 w1 = *(float4*)&sW[d][tc*8+4];
        float av[4] = {a4.x, a4.y, a4.z, a4.w};
        float wv[8] = {w0.x, w0.y, w0.z, w0.w, w1.x, w1.y, w1.z, w1.w};
        #pragma unroll
        for (int i = 0; i < 4; i++)
            #pragma unroll
            for (int j = 0; j < 8; j++) acc[i][j] += av[i] * wv[j];
    }
    __syncthreads();
    // ---- phase 2: rank-embedding part
    for (int i = 0; i < 32; i++) {
        int idx = t + i * 256;
        sW[idx >> 7][idx & 127] = rank_w[(size_t)(d0 + (idx >> 7)) * 128 + (idx & 127)];
    }
    for (int i = 0; i < 16; i++) {
        int idx = t + i * 256;
        int r = idx >> 6, d = idx & 63;
        int dgl = d0 + d;
        float irow = (float)(r0 + r);
        float val;
        if (dgl < 512) {
            float dm = exp2f(-(float)dgl * 0.019464422f);
            val = __sinf(irow * dm);
        } else {
            float dm = exp2f(-(float)(dgl - 512) * 0.019464422f);
            val = __cosf(irow * dm);
        }
        sAT[d][r] = val;
    }
    __syncthreads();
    for (int d = 0; d < 64; d++) {
        float4 a4 = *(float4*)&sAT[d][tr*4];
        float4 w0 = *(float4*)&sW[d][tc*8];
        float4 w1 = *(float4*)&sW[d][tc*8+4];
        float av[4] = {a4.x, a4.y, a4.z, a4.w};
        float wv[8] = {w0.x, w0.y, w0.z, w0.w, w1.x, w1.y, w1.z, w1.w};
        #pragma unroll
        for (int i = 0; i < 4; i++)
            #pragma unroll
            for (int j = 0; j < 8; j++) acc[i][j] += av[i] * wv[j];
    }
    // store partials
    for (int i = 0; i < 4; i++) {
        float* dst = &part[((size_t)dc * 1024 + r0 + tr*4 + i) * 128 + tc*8];
        *(float4*)dst       = make_float4(acc[i][0], acc[i][1], acc[i][2], acc[i][3]);
        *(float4*)(dst + 4) = make_float4(acc[i][4], acc[i][5], acc[i][6], acc[i][7]);
    }
}

// ---------------------------------------------------------------- k_embsum
__global__ void k_embsum(const float* __restrict__ part,
                         const float* __restrict__ feat_b, const float* __restrict__ rank_b,
                         float* __restrict__ emb)
{
    int gid = blockIdx.x * 256 + threadIdx.x;      // 0..131071
    int c = gid & 127;
    float acc = feat_b[c] + rank_b[c];
    for (int dc = 0; dc < 16; dc++) acc += part[(size_t)dc * 131072 + gid];
    emb[gid] = acc;
}

// ---------------------------------------------------------------- k_qkv
__global__ void k_qkv(const float* __restrict__ emb,
                      const float* __restrict__ wq, const float* __restrict__ bq,
                      const float* __restrict__ wk, const float* __restrict__ bk,
                      const float* __restrict__ wv, const float* __restrict__ bv,
                      bf16* __restrict__ q, bf16* __restrict__ k, bf16* __restrict__ v)
{
    __shared__ float et[64][DF];
    int h = blockIdx.x, nt = blockIdx.y, t = threadIdx.x;
    int n0 = nt * 64;
    for (int idx = t; idx < 64 * DF; idx += 256) {
        int r = idx >> 7, c = idx & 127;
        et[r][c] = emb[(n0 + r) * DF + c];
    }
    __syncthreads();
    int kk = t & 63, g = t >> 6;
    const float* Ws[3] = { wq, wk, wv };
    const float* Bs[3] = { bq, bk, bv };
    bf16* Os[3] = { q, k, v };
    for (int m3 = 0; m3 < 3; m3++) {
        float bias = Bs[m3][h * DK + kk];
        float acc[16];
        #pragma unroll
        for (int ii = 0; ii < 16; ii++) acc[ii] = bias;
        for (int d = 0; d < DF; d++) {
            float w = Ws[m3][(h * DF + d) * DK + kk];
            #pragma unroll
            for (int ii = 0; ii < 16; ii++) acc[ii] += et[g*16 + ii][d] * w;
        }
        for (int ii = 0; ii < 16; ii++)
            Os[m3][((size_t)h * N + n0 + g*16 + ii) * DK + kk] = __float2bfloat16(acc[ii]);
    }
}

// ---------------------------------------------------------------- k_attn
// Fused: S = K.Q^T/8 + log(max(relu(posemb.wg+b),1e-6)); softmax_n; O = P.V / Z
// block = (m-tile of 16, head-group of 4); online softmax, no materialized S.
__global__ void __launch_bounds__(256, 2) k_attn(
        const bf16* __restrict__ q, const bf16* __restrict__ kmat,
        const bf16* __restrict__ v, const float* __restrict__ sbbox,
        const float* __restrict__ wgw, const float* __restrict__ wgb,
        bf16* __restrict__ rel)
{
    __shared__ float  sK[HG][TM][68];     // f32 K rows (padded)
    __shared__ ushort sQ[HG][TN][68];     // bf16 Q tile (padded)
    __shared__ ushort sV[HG][TN][68];     // bf16 V tile (padded)
    __shared__ float  sS[HG][TM][33];     // lw -> s -> p (padded)
    __shared__ float  swg[HG][64];
    __shared__ float  sbg[HG];
    __shared__ float  sMax[HG][TM], sZ[HG][TM], sScale[HG][TM];
    __shared__ float  sGm[TM][4];

    int t = threadIdx.x;
    int mt = blockIdx.x, hg = blockIdx.y;
    int m0 = mt * TM, h0 = hg * HG;

    if (t < HG * 64) swg[t >> 6][t & 63] = wgw[(h0 + (t >> 6)) * 64 + (t & 63)];
    if (t < HG) sbg[t] = wgb[h0 + t];
    // K tile: bf16 -> f32
    {
        const uint* ksrc = (const uint*)kmat;
        #pragma unroll
        for (int i = 0; i < 8; i++) {           // 2048 uints
            int fi = t + i * 256;
            int h = fi >> 9, rem = fi & 511;
            int mi = rem >> 5, kp = rem & 31;
            uint u = ksrc[((size_t)(h0 + h) * N + m0 + mi) * 32 + kp];
            sK[h][mi][kp*2]   = __uint_as_float(u << 16);
            sK[h][mi][kp*2+1] = __uint_as_float(u & 0xFFFF0000u);
        }
    }
    if (t < TM) {
        float b0 = sbbox[(m0+t)*4+0], b1 = sbbox[(m0+t)*4+1];
        float b2 = sbbox[(m0+t)*4+2], b3 = sbbox[(m0+t)*4+3];
        sGm[t][0] = (b0 + b2) * 0.5f; sGm[t][1] = (b1 + b3) * 0.5f;
        sGm[t][2] = b2 - b0 + 1.0f;   sGm[t][3] = b3 - b1 + 1.0f;
    }
    if (t < HG * TM) { sMax[t >> 4][t & 15] = -1e30f; sZ[t >> 4][t & 15] = 0.f; }

    float O[4][4];
    #pragma unroll
    for (int i = 0; i < 4; i++)
        #pragma unroll
        for (int j = 0; j < 4; j++) O[i][j] = 0.f;

    const float dmt[8] = { 1.0f, 0.42169650342f, 0.177827941f, 0.0749894209f,
                           0.0316227766f, 0.01333521432f, 0.00562341325f, 0.00237137371f };

    __syncthreads();

    for (int tile = 0; tile < N / TN; tile++) {
        int n0 = tile * TN;
        // ---- load Q/V tiles (global coalesced -> LDS)
        const uint* qsrc = (const uint*)q;
        const uint* vsrc = (const uint*)v;
        #pragma unroll
        for (int h = 0; h < HG; h++) {
            #pragma unroll
            for (int i = 0; i < 4; i++) {       // 1024 uints per head
                int ui = t + i * 256;
                int nj = ui >> 5, kp = ui & 31;
                size_t goff = ((size_t)(h0 + h) * N + n0 + nj) * 32 + kp;
                *(uint*)&sQ[h][nj][kp*2] = qsrc[goff];
                *(uint*)&sV[h][nj][kp*2] = vsrc[goff];
            }
        }
        // ---- A1: positional log-weights, 2 (mi,nj) pairs per thread
        for (int pp = 0; pp < 2; pp++) {
            int pr = t + pp * 256;
            int mi = pr >> 5, nj = pr & 31;
            int n = n0 + nj;
            float b0 = sbbox[n*4+0], b1 = sbbox[n*4+1], b2 = sbbox[n*4+2], b3 = sbbox[n*4+3];
            float cxn = (b0 + b2) * 0.5f, cyn = (b1 + b3) * 0.5f;
            float wn = b2 - b0 + 1.0f, hn = b3 - b1 + 1.0f;
            float cxm = sGm[mi][0], cym = sGm[mi][1], wm = sGm[mi][2], hm = sGm[mi][3];
            float dx = __logf(fmaxf(fabsf((cxm - cxn) / wm), 1e-3f));
            float dy = __logf(fmaxf(fabsf((cym - cyn) / hm), 1e-3f));
            float dw = __logf(wm / wn);
            float dh = __logf(hm / hn);
            float pos[4] = { dx, dy, dw, dh };
            float emb[64];
            #pragma unroll
            for (int c = 0; c < 4; c++)
                #pragma unroll
                for (int f = 0; f < 8; f++) {
                    float arg = 100.0f * pos[c] * dmt[f];
                    emb[c*8 + f]      = __sinf(arg);
                    emb[32 + c*8 + f] = __cosf(arg);
                }
            #pragma unroll
            for (int h = 0; h < HG; h++) {
                float acc = sbg[h];
                #pragma unroll
                for (int eq = 0; eq < 16; eq++) {
                    float4 w4 = *(float4*)&swg[h][eq*4];
                    acc += emb[eq*4]*w4.x + emb[eq*4+1]*w4.y + emb[eq*4+2]*w4.z + emb[eq*4+3]*w4.w;
                }
                acc = fmaxf(acc, 0.f);
                sS[h][mi][nj] = __logf(fmaxf(acc, 1e-6f));
            }
        }
        __syncthreads();
        // ---- A2: qk dot + online-softmax bookkeeping
        {
            int h = t >> 6, a = (t >> 3) & 7, b = t & 7;
            int mi0 = a * 2, mi1 = a * 2 + 1;
            float acc[2][4];
            #pragma unroll
            for (int i = 0; i < 2; i++)
                #pragma unroll
                for (int j = 0; j < 4; j++) acc[i][j] = 0.f;
            #pragma unroll
            for (int kq = 0; kq < 16; kq++) {
                float4 k0 = *(float4*)&sK[h][mi0][kq*4];
                float4 k1 = *(float4*)&sK[h][mi1][kq*4];
                #pragma unroll
                for (int j = 0; j < 4; j++) {
                    int nj = b * 4 + j;
                    uint2 qu = *(uint2*)&sQ[h][nj][kq*4];
                    float q0 = __uint_as_float(qu.x << 16);
                    float q1 = __uint_as_float(qu.x & 0xFFFF0000u);
                    float q2 = __uint_as_float(qu.y << 16);
                    float q3 = __uint_as_float(qu.y & 0xFFFF0000u);
                    acc[0][j] += k0.x*q0 + k0.y*q1 + k0.z*q2 + k0.w*q3;
                    acc[1][j] += k1.x*q0 + k1.y*q1 + k1.z*q2 + k1.w*q3;
                }
            }
            float s[2][4], rmax[2], rsum[2];
            #pragma unroll
            for (int i = 0; i < 2; i++) {
                int mi = a*2 + i;
                #pragma unroll
                for (int j = 0; j < 4; j++)
                    s[i][j] = acc[i][j] * 0.125f + sS[h][mi][b*4 + j];
                rmax[i] = fmaxf(fmaxf(s[i][0], s[i][1]), fmaxf(s[i][2], s[i][3]));
            }
            #pragma unroll
            for (int off = 1; off < 8; off <<= 1) {
                rmax[0] = fmaxf(rmax[0], __shfl_xor(rmax[0], off, 64));
                rmax[1] = fmaxf(rmax[1], __shfl_xor(rmax[1], off, 64));
            }
            float newM[2];
            newM[0] = fmaxf(sMax[h][mi0], rmax[0]);
            newM[1] = fmaxf(sMax[h][mi1], rmax[1]);
            #pragma unroll
            for (int i = 0; i < 2; i++) {
                int mi = a*2 + i;
                float rs = 0.f;
                #pragma unroll
                for (int j = 0; j < 4; j++) {
                    float p = __expf(s[i][j] - newM[i]);
                    sS[h][mi][b*4 + j] = p;
                    rs += p;
                }
                rsum[i] = rs;
            }
            #pragma unroll
            for (int off = 1; off < 8; off <<= 1) {
                rsum[0] += __shfl_xor(rsum[0], off, 64);
                rsum[1] += __shfl_xor(rsum[1], off, 64);
            }
            if (b == 0) {
                #pragma unroll
                for (int i = 0; i < 2; i++) {
                    int mi = a*2 + i;
                    float sc = __expf(sMax[h][mi] - newM[i]);
                    sScale[h][mi] = sc;
                    sMax[h][mi] = newM[i];
                    sZ[h][mi] = sZ[h][mi] * sc + rsum[i];
                }
            }
        }
        __syncthreads();
        // ---- PV: O = O*scale + P.V
        {
            int h = t >> 6, am = (t >> 4) & 3, bk = t & 15;
            float sc[4];
            #pragma unroll
            for (int i = 0; i < 4; i++) sc[i] = sScale[h][am*4 + i];
            #pragma unroll
            for (int i = 0; i < 4; i++)
                #pragma unroll
                for (int j = 0; j < 4; j++) O[i][j] *= sc[i];
            for (int nj = 0; nj < TN; nj++) {
                uint2 vu = *(uint2*)&sV[h][nj][bk*4];
                float v0 = __uint_as_float(vu.x << 16);
                float v1 = __uint_as_float(vu.x & 0xFFFF0000u);
                float v2 = __uint_as_float(vu.y << 16);
                float v3 = __uint_as_float(vu.y & 0xFFFF0000u);
                #pragma unroll
                for (int i = 0; i < 4; i++) {
                    float p = sS[h][am*4 + i][nj];
                    O[i][0] += p * v0; O[i][1] += p * v1;
                    O[i][2] += p * v2; O[i][3] += p * v3;
                }
            }
        }
        __syncthreads();
    }
    // ---- epilogue: normalize, store rel (bf16)
    {
        int h = t >> 6, am = (t >> 4) & 3, bk = t & 15;
        #pragma unroll
        for (int i = 0; i < 4; i++) {
            int m = m0 + am*4 + i;
            float inv = 1.0f / sZ[h][am*4 + i];
            #pragma unroll
            for (int j = 0; j < 4; j++)
                rel[((size_t)(h0 + h) * N + m) * 64 + bk*4 + j] = __float2bfloat16(O[i][j] * inv);
        }
    }
}

// ---------------------------------------------------------------- k_final
__global__ void k_final(const bf16* __restrict__ rel, const int* __restrict__ order,
                        const float* __restrict__ app, const float* __restrict__ lw,
                        const float* __restrict__ lb, const float* __restrict__ sprob,
                        float* __restrict__ out)
{
    __shared__ float red[2];
    int m = blockIdx.x, t = threadIdx.x;   // 128 threads
    int o = order[m];
    float s = 0.f;
    for (int j = t; j < APP; j += 128) {
        int hh = j >> 6, kk = j & 63;
        float rv = b2f(rel[((size_t)hh * N + m) * DK + kk]) + app[o * APP + j];
        s += rv * lw[j];
    }
    #pragma unroll
    for (int off = 32; off > 0; off >>= 1) s += __shfl_down(s, off, 64);
    if ((t & 63) == 0) red[t >> 6] = s;
    __syncthreads();
    if (t == 0) {
        float tot = red[0] + red[1] + lb[0];
        float s1 = 1.0f / (1.0f + expf(-tot));
        out[m] = s1 * sprob[m];
    }
}

// ---------------------------------------------------------------- launch
extern "C" void kernel_launch(void* const* d_in, const int* in_sizes, int n_in,
                              void* d_out, int out_size, void* d_ws, size_t ws_size,
                              hipStream_t stream)
{
    const float* roi      = (const float*)d_in[0];
    const float* cls_loc  = (const float*)d_in[1];
    const float* score    = (const float*)d_in[2];
    const float* app      = (const float*)d_in[3];
    const int*   size     = (const int*)d_in[4];
    const float* rank_w   = (const float*)d_in[5];
    const float* rank_b   = (const float*)d_in[6];
    const float* feat_w   = (const float*)d_in[7];
    const float* feat_b   = (const float*)d_in[8];
    const float* logit_w  = (const float*)d_in[9];
    const float* logit_b  = (const float*)d_in[10];
    const float* wg_w     = (const float*)d_in[11];
    const float* wg_b     = (const float*)d_in[12];
    const float* wk_w     = (const float*)d_in[13];
    const float* wk_b     = (const float*)d_in[14];
    const float* wq_w     = (const float*)d_in[15];
    const float* wq_b     = (const float*)d_in[16];
    const float* wv_w     = (const float*)d_in[17];
    const float* wv_b     = (const float*)d_in[18];
    float* out = (float*)d_out;   // f32: [scores 1024 | labels 1024 | bbox 4096]

    char* ws = (char*)d_ws;
    float* prob  = (float*)(ws + 0);
    int*   label = (int*)  (ws + 4096);
    float* bbox  = (float*)(ws + 8192);
    u64*   keys  = (u64*)  (ws + 24576);
    int*   order = (int*)  (ws + 32768);
    float* sprob = (float*)(ws + 36864);
    float* sbbox = (float*)(ws + 40960);
    float* emb   = (float*)(ws + 57344);      // 512 KB
    float* part  = (float*)(ws + 581632);     // 8 MB  [16][1024][128]
    bf16*  q     = (bf16*) (ws + 8970240);    // 2 MB
    bf16*  k     = (bf16*) (ws + 11067392);   // 2 MB
    bf16*  v     = (bf16*) (ws + 13164544);   // 2 MB
    bf16*  rel   = (bf16*) (ws + 15261696);   // 2 MB

    k_prep<<<4, 256, 0, stream>>>(roi, cls_loc, score, size, prob, label, bbox, keys);
    k_sort<<<1, 1024, 0, stream>>>(keys, prob, label, bbox, order, sprob, sbbox, out);
    k_emb<<<dim3(16, 16), 256, 0, stream>>>(order, app, feat_w, rank_w, part);
    k_embsum<<<512, 256, 0, stream>>>(part, feat_b, rank_b, emb);
    k_qkv<<<dim3(16, 16), 256, 0, stream>>>(emb, wq_w, wq_b, wk_w, wk_b, wv_w, wv_b, q, k, v);
    k_attn<<<dim3(64, 4), 256, 0, stream>>>(q, k, v, sbbox, wg_w, wg_b, rel);
    k_final<<<1024, 128, 0, stream>>>(rel, order, app, logit_w, logit_b, sprob, out);
}

// Round 5
// 402.451 us; speedup vs baseline: 1.6672x; 1.5248x over previous
//
#include <hip/hip_runtime.h>
#include <hip/hip_bf16.h>
#include <math.h>

typedef unsigned long long u64;
typedef unsigned int u32;
typedef __hip_bfloat16 bf16;

#define N 1024
#define NCLS 21
#define APP 1024
#define DF 128
#define NH 16
#define DK 64

__device__ __forceinline__ float b2f(bf16 x) { return __bfloat162float(x); }
__device__ __forceinline__ ushort f2bu(float x) { bf16 b = __float2bfloat16(x); return *(ushort*)&b; }

// ---------------------------------------------------------------- k_prep
__global__ void k_prep(const float* __restrict__ roi, const float* __restrict__ cls_loc,
                       const float* __restrict__ score, const int* __restrict__ size,
                       float* __restrict__ prob, int* __restrict__ label,
                       float* __restrict__ bbox, u64* __restrict__ keys)
{
    int i = blockIdx.x * 256 + threadIdx.x;
    if (i >= N) return;
    float s[NCLS];
    float mx = -1e30f; int am = 0;
    for (int c = 0; c < NCLS; c++) {
        s[c] = score[i * NCLS + c];
        if (s[c] > mx) { mx = s[c]; am = c; }
    }
    float sum = 0.f;
    for (int c = 0; c < NCLS; c++) sum += expf(s[c] - mx);
    float p = 1.0f / sum;

    float y0 = roi[i*4+0], x0 = roi[i*4+1];
    float y1 = roi[i*4+2], x1 = roi[i*4+3];
    float hh = y1 - y0, ww = x1 - x0;
    float cy = y0 + 0.5f * hh, cx = x0 + 0.5f * ww;
    float l0 = cls_loc[i*84 + am*4 + 0] * 0.1f;
    float l1 = cls_loc[i*84 + am*4 + 1] * 0.1f;
    float l2 = cls_loc[i*84 + am*4 + 2] * 0.2f;
    float l3 = cls_loc[i*84 + am*4 + 3] * 0.2f;
    float ncy = l0 * hh + cy, ncx = l1 * ww + cx;
    float nh = expf(l2) * hh, nw = expf(l3) * ww;
    float b0 = ncy - 0.5f * nh, b1 = ncx - 0.5f * nw;
    float b2v = ncy + 0.5f * nh, b3 = ncx + 0.5f * nw;
    float lim = ((am & 1) == 0) ? (float)size[0] : (float)size[1];
    b0  = fminf(fmaxf(b0, 0.f), lim);
    b1  = fminf(fmaxf(b1, 0.f), lim);
    b2v = fminf(fmaxf(b2v, 0.f), lim);
    b3  = fminf(fmaxf(b3, 0.f), lim);
    prob[i] = p; label[i] = am;
    bbox[i*4+0] = b0; bbox[i*4+1] = b1; bbox[i*4+2] = b2v; bbox[i*4+3] = b3;
    keys[i] = ((u64)(0xFFFFFFFFu - __float_as_uint(p)) << 32) | (u32)i;
}

// ---------------------------------------------------------------- k_sort
__global__ void __launch_bounds__(1024) k_sort(
        const u64* __restrict__ keys, const float* __restrict__ prob,
        const int* __restrict__ label, const float* __restrict__ bbox,
        int* __restrict__ order, float* __restrict__ sprob,
        float* __restrict__ sbbox, float* __restrict__ out)
{
    __shared__ u64 sk[N];
    int t = threadIdx.x;
    sk[t] = keys[t];
    __syncthreads();
    for (int k = 2; k <= N; k <<= 1) {
        for (int j = k >> 1; j > 0; j >>= 1) {
            int p = t ^ j;
            if (p > t) {
                u64 a = sk[t], b = sk[p];
                bool up = ((t & k) == 0);
                if ((a > b) == up) { sk[t] = b; sk[p] = a; }
            }
            __syncthreads();
        }
    }
    int o = (int)(sk[t] & 0xFFFFFFFFull);
    order[t] = o;
    sprob[t] = prob[o];
    float b0 = bbox[o*4+0], b1 = bbox[o*4+1], b2 = bbox[o*4+2], b3 = bbox[o*4+3];
    sbbox[t*4+0] = b0; sbbox[t*4+1] = b1; sbbox[t*4+2] = b2; sbbox[t*4+3] = b3;
    out[N + t] = (float)(label[o] - 1);
    out[2*N + t*4 + 0] = b0;
    out[2*N + t*4 + 1] = b1;
    out[2*N + t*4 + 2] = b2;
    out[2*N + t*4 + 3] = b3;
}

// ---------------------------------------------------------------- k_emb (split-K partials)
__global__ void __launch_bounds__(256) k_emb(
        const int* __restrict__ order, const float* __restrict__ app,
        const float* __restrict__ feat_w, const float* __restrict__ rank_w,
        float* __restrict__ part)
{
    __shared__ float sAT[64][68];
    __shared__ float sW[64][128];
    __shared__ int sOrd[64];
    int rt = blockIdx.x, dc = blockIdx.y, t = threadIdx.x;
    int r0 = rt * 64, d0 = dc * 64;
    if (t < 64) sOrd[t] = order[r0 + t];
    __syncthreads();
    for (int i = 0; i < 32; i++) {
        int idx = t + i * 256;
        sW[idx >> 7][idx & 127] = feat_w[(size_t)(d0 + (idx >> 7)) * 128 + (idx & 127)];
    }
    for (int i = 0; i < 16; i++) {
        int idx = t + i * 256;
        int r = idx >> 6, d = idx & 63;
        sAT[d][r] = app[(size_t)sOrd[r] * 1024 + d0 + d];
    }
    __syncthreads();
    int tr = t >> 4, tc = t & 15;
    float acc[4][8];
    #pragma unroll
    for (int i = 0; i < 4; i++)
        #pragma unroll
        for (int j = 0; j < 8; j++) acc[i][j] = 0.f;
    for (int d = 0; d < 64; d++) {
        float4 a4 = *(float4*)&sAT[d][tr*4];
        float4 w0 = *(float4*)&sW[d][tc*8];
        float4 w1 = *(float4*)&sW[d][tc*8+4];
        float av[4] = {a4.x, a4.y, a4.z, a4.w};
        float wv[8] = {w0.x, w0.y, w0.z, w0.w, w1.x, w1.y, w1.z, w1.w};
        #pragma unroll
        for (int i = 0; i < 4; i++)
            #pragma unroll
            for (int j = 0; j < 8; j++) acc[i][j] += av[i] * wv[j];
    }
    __syncthreads();
    for (int i = 0; i < 32; i++) {
        int idx = t + i * 256;
        sW[idx >> 7][idx & 127] = rank_w[(size_t)(d0 + (idx >> 7)) * 128 + (idx & 127)];
    }
    for (int i = 0; i < 16; i++) {
        int idx = t + i * 256;
        int r = idx >> 6, d = idx & 63;
        int dgl = d0 + d;
        float irow = (float)(r0 + r);
        float val;
        if (dgl < 512) {
            float dm = exp2f(-(float)dgl * 0.019464422f);
            val = __sinf(irow * dm);
        } else {
            float dm = exp2f(-(float)(dgl - 512) * 0.019464422f);
            val = __cosf(irow * dm);
        }
        sAT[d][r] = val;
    }
    __syncthreads();
    for (int d = 0; d < 64; d++) {
        float4 a4 = *(float4*)&sAT[d][tr*4];
        float4 w0 = *(float4*)&sW[d][tc*8];
        float4 w1 = *(float4*)&sW[d][tc*8+4];
        float av[4] = {a4.x, a4.y, a4.z, a4.w};
        float wv[8] = {w0.x, w0.y, w0.z, w0.w, w1.x, w1.y, w1.z, w1.w};
        #pragma unroll
        for (int i = 0; i < 4; i++)
            #pragma unroll
            for (int j = 0; j < 8; j++) acc[i][j] += av[i] * wv[j];
    }
    for (int i = 0; i < 4; i++) {
        float* dst = &part[((size_t)dc * 1024 + r0 + tr*4 + i) * 128 + tc*8];
        *(float4*)dst       = make_float4(acc[i][0], acc[i][1], acc[i][2], acc[i][3]);
        *(float4*)(dst + 4) = make_float4(acc[i][4], acc[i][5], acc[i][6], acc[i][7]);
    }
}

// ---------------------------------------------------------------- k_embsum
__global__ void k_embsum(const float* __restrict__ part,
                         const float* __restrict__ feat_b, const float* __restrict__ rank_b,
                         float* __restrict__ emb)
{
    int gid = blockIdx.x * 256 + threadIdx.x;
    int c = gid & 127;
    float acc = feat_b[c] + rank_b[c];
    for (int dc = 0; dc < 16; dc++) acc += part[(size_t)dc * 131072 + gid];
    emb[gid] = acc;
}

// ---------------------------------------------------------------- k_qkv
__global__ void k_qkv(const float* __restrict__ emb,
                      const float* __restrict__ wq, const float* __restrict__ bq,
                      const float* __restrict__ wk, const float* __restrict__ bk,
                      const float* __restrict__ wv, const float* __restrict__ bv,
                      bf16* __restrict__ q, bf16* __restrict__ k, bf16* __restrict__ v)
{
    __shared__ float et[64][DF];
    int h = blockIdx.x, nt = blockIdx.y, t = threadIdx.x;
    int n0 = nt * 64;
    for (int idx = t; idx < 64 * DF; idx += 256) {
        int r = idx >> 7, c = idx & 127;
        et[r][c] = emb[(n0 + r) * DF + c];
    }
    __syncthreads();
    int kk = t & 63, g = t >> 6;
    const float* Ws[3] = { wq, wk, wv };
    const float* Bs[3] = { bq, bk, bv };
    bf16* Os[3] = { q, k, v };
    for (int m3 = 0; m3 < 3; m3++) {
        float bias = Bs[m3][h * DK + kk];
        float acc[16];
        #pragma unroll
        for (int ii = 0; ii < 16; ii++) acc[ii] = bias;
        for (int d = 0; d < DF; d++) {
            float w = Ws[m3][(h * DF + d) * DK + kk];
            #pragma unroll
            for (int ii = 0; ii < 16; ii++) acc[ii] += et[g*16 + ii][d] * w;
        }
        for (int ii = 0; ii < 16; ii++)
            Os[m3][((size_t)h * N + n0 + g*16 + ii) * DK + kk] = __float2bfloat16(acc[ii]);
    }
}

// ---------------------------------------------------------------- k_geo
// lw[h,m,n] = log(max(relu(posemb(m,n).wg_w[h] + wg_b[h]), 1e-6))  (write-once)
__global__ void __launch_bounds__(256) k_geo(
        const float* __restrict__ sbbox, const float* __restrict__ wgw,
        const float* __restrict__ wgb, bf16* __restrict__ lw)
{
    __shared__ float sw[NH][64];
    __shared__ float sb[NH];
    __shared__ float mbb[4];
    int m = blockIdx.x, nc = blockIdx.y, t = threadIdx.x;
    for (int idx = t; idx < NH * 64; idx += 256) sw[idx >> 6][idx & 63] = wgw[idx];
    if (t < NH) sb[t] = wgb[t];
    if (t == 0) {
        float b0 = sbbox[m*4+0], b1 = sbbox[m*4+1], b2 = sbbox[m*4+2], b3 = sbbox[m*4+3];
        mbb[0] = (b0 + b2) * 0.5f; mbb[1] = (b1 + b3) * 0.5f;
        mbb[2] = b2 - b0 + 1.0f;   mbb[3] = b3 - b1 + 1.0f;
    }
    __syncthreads();
    int n = nc * 256 + t;
    float b0 = sbbox[n*4+0], b1 = sbbox[n*4+1], b2 = sbbox[n*4+2], b3 = sbbox[n*4+3];
    float cxn = (b0 + b2) * 0.5f, cyn = (b1 + b3) * 0.5f;
    float wn = b2 - b0 + 1.0f, hn = b3 - b1 + 1.0f;
    float dx = __logf(fmaxf(fabsf((mbb[0] - cxn) / mbb[2]), 1e-3f));
    float dy = __logf(fmaxf(fabsf((mbb[1] - cyn) / mbb[3]), 1e-3f));
    float dw = __logf(mbb[2] / wn);
    float dh = __logf(mbb[3] / hn);
    float pos[4] = { dx, dy, dw, dh };
    const float dmt[8] = { 1.0f, 0.42169650342f, 0.177827941f, 0.0749894209f,
                           0.0316227766f, 0.01333521432f, 0.00562341325f, 0.00237137371f };
    float emb[64];
    #pragma unroll
    for (int c = 0; c < 4; c++)
        #pragma unroll
        for (int f = 0; f < 8; f++) {
            float arg = 100.0f * pos[c] * dmt[f];
            emb[c*8 + f]      = __sinf(arg);
            emb[32 + c*8 + f] = __cosf(arg);
        }
    size_t base = ((size_t)m << 10) + n;
    #pragma unroll
    for (int hh = 0; hh < NH; hh++) {
        float wg = sb[hh];
        #pragma unroll
        for (int e = 0; e < 16; e++) {
            float4 w4 = *(float4*)&sw[hh][e*4];
            wg += emb[e*4]*w4.x + emb[e*4+1]*w4.y + emb[e*4+2]*w4.z + emb[e*4+3]*w4.w;
        }
        wg = fmaxf(wg, 0.f);
        lw[((size_t)hh << 20) + base] = __float2bfloat16(__logf(fmaxf(wg, 1e-6f)));
    }
}

// ---------------------------------------------------------------- k_attn2
// Flash-style: per block = (head, 32-row m-tile). S = K.Q^T/8 + lw; online
// softmax over n; O = P.V / Z.  Grid 512 blocks, LDS ~35 KB.
__global__ void __launch_bounds__(256, 2) k_attn2(
        const bf16* __restrict__ q, const bf16* __restrict__ kmat,
        const bf16* __restrict__ v, const bf16* __restrict__ lw,
        bf16* __restrict__ rel)
{
    __shared__ float  sK[32][66];      // K tile f32, resident all kernel
    __shared__ ushort sQ[64][70];      // Q n-tile bf16 (pad 70: 2-way banks)
    __shared__ ushort sV[64][70];      // V n-tile bf16
    __shared__ float  sP[32][66];      // P tile f32

    int t = threadIdx.x;
    int mt = blockIdx.x, h = blockIdx.y;
    int m0 = mt * 32;
    int tr = t >> 5;          // 0..7  -> rows m0 + tr*4 .. +4
    int tc = t & 31;          // 0..31 -> cols 2tc, 2tc+1 (both n and k)

    // prologue: K tile bf16 -> f32 LDS
    {
        const uint* ksrc = (const uint*)kmat;
        #pragma unroll
        for (int i = 0; i < 4; i++) {
            int idx = t + i * 256;            // 1024 uints = 32 rows x 32
            int mi = idx >> 5, kp = idx & 31;
            uint u = ksrc[((size_t)h * N + m0 + mi) * 32 + kp];
            *(float2*)&sK[mi][kp*2] = make_float2(
                __uint_as_float(u << 16), __uint_as_float(u & 0xFFFF0000u));
        }
    }

    float O[4][2];
    float M[4], Z[4];
    #pragma unroll
    for (int i = 0; i < 4; i++) {
        M[i] = -1e30f; Z[i] = 0.f; O[i][0] = 0.f; O[i][1] = 0.f;
    }

    const uint* qsrc = (const uint*)q;
    const uint* vsrc = (const uint*)v;
    const uint* lwsrc = (const uint*)lw;

    for (int tile = 0; tile < 16; tile++) {
        int n0 = tile * 64;
        // load Q/V n-tiles
        #pragma unroll
        for (int i = 0; i < 8; i++) {
            int idx = t + i * 256;            // 2048 uints = 64 rows x 32
            int nj = idx >> 5, kp = idx & 31;
            size_t goff = ((size_t)h * N + n0 + nj) * 32 + kp;
            *(uint*)&sQ[nj][kp*2] = qsrc[goff];
            *(uint*)&sV[nj][kp*2] = vsrc[goff];
        }
        __syncthreads();

        // S = K.Q^T/8 + lw  for rows mi=tr*4+i, cols nj=2tc,2tc+1
        float s[4][2];
        {
            float acc[4][2];
            #pragma unroll
            for (int i = 0; i < 4; i++) { acc[i][0] = 0.f; acc[i][1] = 0.f; }
            int nj0 = 2 * tc, nj1 = 2 * tc + 1;
            #pragma unroll
            for (int kq = 0; kq < 16; kq++) {
                uint qa0 = *(uint*)&sQ[nj0][kq*4];
                uint qa1 = *(uint*)&sQ[nj0][kq*4+2];
                uint qb0 = *(uint*)&sQ[nj1][kq*4];
                uint qb1 = *(uint*)&sQ[nj1][kq*4+2];
                float q00 = __uint_as_float(qa0 << 16), q01 = __uint_as_float(qa0 & 0xFFFF0000u);
                float q02 = __uint_as_float(qa1 << 16), q03 = __uint_as_float(qa1 & 0xFFFF0000u);
                float q10 = __uint_as_float(qb0 << 16), q11 = __uint_as_float(qb0 & 0xFFFF0000u);
                float q12 = __uint_as_float(qb1 << 16), q13 = __uint_as_float(qb1 & 0xFFFF0000u);
                #pragma unroll
                for (int i = 0; i < 4; i++) {
                    float4 kv = *(float4*)&sK[tr*4 + i][kq*4];
                    acc[i][0] += kv.x*q00 + kv.y*q01 + kv.z*q02 + kv.w*q03;
                    acc[i][1] += kv.x*q10 + kv.y*q11 + kv.z*q12 + kv.w*q13;
                }
            }
            #pragma unroll
            for (int i = 0; i < 4; i++) {
                int m = m0 + tr*4 + i;
                uint lu = lwsrc[((size_t)h << 19) + ((size_t)m << 9) + (n0 >> 1) + tc];
                float l0 = __uint_as_float(lu << 16);
                float l1 = __uint_as_float(lu & 0xFFFF0000u);
                s[i][0] = acc[i][0] * 0.125f + l0;
                s[i][1] = acc[i][1] * 0.125f + l1;
            }
        }
        // online softmax bookkeeping (row spread over 32 lanes sharing tr)
        float sc[4];
        #pragma unroll
        for (int i = 0; i < 4; i++) {
            float rm = fmaxf(s[i][0], s[i][1]);
            #pragma unroll
            for (int off = 1; off < 32; off <<= 1)
                rm = fmaxf(rm, __shfl_xor(rm, off, 64));
            float newM = fmaxf(M[i], rm);
            float p0 = __expf(s[i][0] - newM);
            float p1 = __expf(s[i][1] - newM);
            float rs = p0 + p1;
            #pragma unroll
            for (int off = 1; off < 32; off <<= 1)
                rs += __shfl_xor(rs, off, 64);
            sc[i] = __expf(M[i] - newM);
            Z[i] = Z[i] * sc[i] + rs;
            M[i] = newM;
            sP[tr*4 + i][2*tc]   = p0;
            sP[tr*4 + i][2*tc+1] = p1;
            O[i][0] *= sc[i];
            O[i][1] *= sc[i];
        }
        __syncthreads();
        // PV: O[mi][k] += sum_n P[mi][n] * V[n][k], k = 2tc, 2tc+1
        for (int n = 0; n < 64; n++) {
            uint vu = *(uint*)&sV[n][2*tc];
            float v0 = __uint_as_float(vu << 16);
            float v1 = __uint_as_float(vu & 0xFFFF0000u);
            #pragma unroll
            for (int i = 0; i < 4; i++) {
                float p = sP[tr*4 + i][n];
                O[i][0] += p * v0;
                O[i][1] += p * v1;
            }
        }
        __syncthreads();
    }
    // epilogue
    {
        uint* relu32 = (uint*)rel;
        #pragma unroll
        for (int i = 0; i < 4; i++) {
            int m = m0 + tr*4 + i;
            float inv = 1.0f / Z[i];
            uint lo = (uint)f2bu(O[i][0] * inv);
            uint hi = (uint)f2bu(O[i][1] * inv);
            relu32[((size_t)h * N + m) * 32 + tc] = lo | (hi << 16);
        }
    }
}

// ---------------------------------------------------------------- k_final
__global__ void k_final(const bf16* __restrict__ rel, const int* __restrict__ order,
                        const float* __restrict__ app, const float* __restrict__ lw,
                        const float* __restrict__ lb, const float* __restrict__ sprob,
                        float* __restrict__ out)
{
    __shared__ float red[2];
    int m = blockIdx.x, t = threadIdx.x;
    int o = order[m];
    float s = 0.f;
    for (int j = t; j < APP; j += 128) {
        int hh = j >> 6, kk = j & 63;
        float rv = b2f(rel[((size_t)hh * N + m) * DK + kk]) + app[o * APP + j];
        s += rv * lw[j];
    }
    #pragma unroll
    for (int off = 32; off > 0; off >>= 1) s += __shfl_down(s, off, 64);
    if ((t & 63) == 0) red[t >> 6] = s;
    __syncthreads();
    if (t == 0) {
        float tot = red[0] + red[1] + lb[0];
        float s1 = 1.0f / (1.0f + expf(-tot));
        out[m] = s1 * sprob[m];
    }
}

// ---------------------------------------------------------------- launch
extern "C" void kernel_launch(void* const* d_in, const int* in_sizes, int n_in,
                              void* d_out, int out_size, void* d_ws, size_t ws_size,
                              hipStream_t stream)
{
    const float* roi      = (const float*)d_in[0];
    const float* cls_loc  = (const float*)d_in[1];
    const float* score    = (const float*)d_in[2];
    const float* app      = (const float*)d_in[3];
    const int*   size     = (const int*)d_in[4];
    const float* rank_w   = (const float*)d_in[5];
    const float* rank_b   = (const float*)d_in[6];
    const float* feat_w   = (const float*)d_in[7];
    const float* feat_b   = (const float*)d_in[8];
    const float* logit_w  = (const float*)d_in[9];
    const float* logit_b  = (const float*)d_in[10];
    const float* wg_w     = (const float*)d_in[11];
    const float* wg_b     = (const float*)d_in[12];
    const float* wk_w     = (const float*)d_in[13];
    const float* wk_b     = (const float*)d_in[14];
    const float* wq_w     = (const float*)d_in[15];
    const float* wq_b     = (const float*)d_in[16];
    const float* wv_w     = (const float*)d_in[17];
    const float* wv_b     = (const float*)d_in[18];
    float* out = (float*)d_out;

    char* ws = (char*)d_ws;
    float* prob  = (float*)(ws + 0);
    int*   label = (int*)  (ws + 4096);
    float* bbox  = (float*)(ws + 8192);
    u64*   keys  = (u64*)  (ws + 24576);
    int*   order = (int*)  (ws + 32768);
    float* sprob = (float*)(ws + 36864);
    float* sbbox = (float*)(ws + 40960);
    float* emb   = (float*)(ws + 57344);      // 512 KB
    float* part  = (float*)(ws + 581632);     // 8 MB
    bf16*  q     = (bf16*) (ws + 8970240);    // 2 MB
    bf16*  k     = (bf16*) (ws + 11067392);   // 2 MB
    bf16*  v     = (bf16*) (ws + 13164544);   // 2 MB
    bf16*  rel   = (bf16*) (ws + 15261696);   // 2 MB
    bf16*  lwbuf = (bf16*) (ws + 17358848);   // 32 MB  (total 50.9 MB, proven to fit)

    k_prep<<<4, 256, 0, stream>>>(roi, cls_loc, score, size, prob, label, bbox, keys);
    k_sort<<<1, 1024, 0, stream>>>(keys, prob, label, bbox, order, sprob, sbbox, out);
    k_emb<<<dim3(16, 16), 256, 0, stream>>>(order, app, feat_w, rank_w, part);
    k_embsum<<<512, 256, 0, stream>>>(part, feat_b, rank_b, emb);
    k_qkv<<<dim3(16, 16), 256, 0, stream>>>(emb, wq_w, wq_b, wk_w, wk_b, wv_w, wv_b, q, k, v);
    k_geo<<<dim3(1024, 4), 256, 0, stream>>>(sbbox, wg_w, wg_b, lwbuf);
    k_attn2<<<dim3(32, 16), 256, 0, stream>>>(q, k, v, lwbuf, rel);
    k_final<<<1024, 128, 0, stream>>>(rel, order, app, logit_w, logit_b, sprob, out);
}

// Round 6
// 254.593 us; speedup vs baseline: 2.6355x; 1.5808x over previous
//
#include <hip/hip_runtime.h>
#include <hip/hip_bf16.h>
#include <math.h>

typedef unsigned long long u64;
typedef unsigned int u32;
typedef __hip_bfloat16 bf16;

#define N 1024
#define NCLS 21
#define APP 1024
#define DF 128
#define NH 16
#define DK 64

typedef __attribute__((ext_vector_type(8))) short short8v;
typedef __attribute__((ext_vector_type(4))) float float4v;
union U4S8 { uint4 u; short8v s; };

__device__ __forceinline__ float b2f(bf16 x) { return __bfloat162float(x); }
__device__ __forceinline__ ushort f2bu(float x) { bf16 b = __float2bfloat16(x); return *(ushort*)&b; }
__device__ __forceinline__ float bu2f(ushort u) { uint v = ((uint)u) << 16; return __uint_as_float(v); }

// ---------------------------------------------------------------- k_prep
__global__ void k_prep(const float* __restrict__ roi, const float* __restrict__ cls_loc,
                       const float* __restrict__ score, const int* __restrict__ size,
                       float* __restrict__ prob, int* __restrict__ label,
                       float* __restrict__ bbox, u64* __restrict__ keys)
{
    int i = blockIdx.x * 256 + threadIdx.x;
    if (i >= N) return;
    float s[NCLS];
    float mx = -1e30f; int am = 0;
    for (int c = 0; c < NCLS; c++) {
        s[c] = score[i * NCLS + c];
        if (s[c] > mx) { mx = s[c]; am = c; }
    }
    float sum = 0.f;
    for (int c = 0; c < NCLS; c++) sum += expf(s[c] - mx);
    float p = 1.0f / sum;

    float y0 = roi[i*4+0], x0 = roi[i*4+1];
    float y1 = roi[i*4+2], x1 = roi[i*4+3];
    float hh = y1 - y0, ww = x1 - x0;
    float cy = y0 + 0.5f * hh, cx = x0 + 0.5f * ww;
    float l0 = cls_loc[i*84 + am*4 + 0] * 0.1f;
    float l1 = cls_loc[i*84 + am*4 + 1] * 0.1f;
    float l2 = cls_loc[i*84 + am*4 + 2] * 0.2f;
    float l3 = cls_loc[i*84 + am*4 + 3] * 0.2f;
    float ncy = l0 * hh + cy, ncx = l1 * ww + cx;
    float nh = expf(l2) * hh, nw = expf(l3) * ww;
    float b0 = ncy - 0.5f * nh, b1 = ncx - 0.5f * nw;
    float b2v = ncy + 0.5f * nh, b3 = ncx + 0.5f * nw;
    float lim = ((am & 1) == 0) ? (float)size[0] : (float)size[1];
    b0  = fminf(fmaxf(b0, 0.f), lim);
    b1  = fminf(fmaxf(b1, 0.f), lim);
    b2v = fminf(fmaxf(b2v, 0.f), lim);
    b3  = fminf(fmaxf(b3, 0.f), lim);
    prob[i] = p; label[i] = am;
    bbox[i*4+0] = b0; bbox[i*4+1] = b1; bbox[i*4+2] = b2v; bbox[i*4+3] = b3;
    keys[i] = ((u64)(0xFFFFFFFFu - __float_as_uint(p)) << 32) | (u32)i;
}

// ---------------------------------------------------------------- k_sort
__global__ void __launch_bounds__(1024) k_sort(
        const u64* __restrict__ keys, const float* __restrict__ prob,
        const int* __restrict__ label, const float* __restrict__ bbox,
        int* __restrict__ order, float* __restrict__ sprob,
        float* __restrict__ sbbox, float* __restrict__ out)
{
    __shared__ u64 sk[N];
    int t = threadIdx.x;
    sk[t] = keys[t];
    __syncthreads();
    for (int k = 2; k <= N; k <<= 1) {
        for (int j = k >> 1; j > 0; j >>= 1) {
            int p = t ^ j;
            if (p > t) {
                u64 a = sk[t], b = sk[p];
                bool up = ((t & k) == 0);
                if ((a > b) == up) { sk[t] = b; sk[p] = a; }
            }
            __syncthreads();
        }
    }
    int o = (int)(sk[t] & 0xFFFFFFFFull);
    order[t] = o;
    sprob[t] = prob[o];
    float b0 = bbox[o*4+0], b1 = bbox[o*4+1], b2 = bbox[o*4+2], b3 = bbox[o*4+3];
    sbbox[t*4+0] = b0; sbbox[t*4+1] = b1; sbbox[t*4+2] = b2; sbbox[t*4+3] = b3;
    out[N + t] = (float)(label[o] - 1);
    out[2*N + t*4 + 0] = b0;
    out[2*N + t*4 + 1] = b1;
    out[2*N + t*4 + 2] = b2;
    out[2*N + t*4 + 3] = b3;
}

// ---------------------------------------------------------------- k_emb (split-K partials)
__global__ void __launch_bounds__(256) k_emb(
        const int* __restrict__ order, const float* __restrict__ app,
        const float* __restrict__ feat_w, const float* __restrict__ rank_w,
        float* __restrict__ part)
{
    __shared__ float sAT[64][68];
    __shared__ float sW[64][128];
    __shared__ int sOrd[64];
    int rt = blockIdx.x, dc = blockIdx.y, t = threadIdx.x;
    int r0 = rt * 64, d0 = dc * 64;
    if (t < 64) sOrd[t] = order[r0 + t];
    __syncthreads();
    for (int i = 0; i < 32; i++) {
        int idx = t + i * 256;
        sW[idx >> 7][idx & 127] = feat_w[(size_t)(d0 + (idx >> 7)) * 128 + (idx & 127)];
    }
    for (int i = 0; i < 16; i++) {
        int idx = t + i * 256;
        int r = idx >> 6, d = idx & 63;
        sAT[d][r] = app[(size_t)sOrd[r] * 1024 + d0 + d];
    }
    __syncthreads();
    int tr = t >> 4, tc = t & 15;
    float acc[4][8];
    #pragma unroll
    for (int i = 0; i < 4; i++)
        #pragma unroll
        for (int j = 0; j < 8; j++) acc[i][j] = 0.f;
    for (int d = 0; d < 64; d++) {
        float4 a4 = *(float4*)&sAT[d][tr*4];
        float4 w0 = *(float4*)&sW[d][tc*8];
        float4 w1 = *(float4*)&sW[d][tc*8+4];
        float av[4] = {a4.x, a4.y, a4.z, a4.w};
        float wv[8] = {w0.x, w0.y, w0.z, w0.w, w1.x, w1.y, w1.z, w1.w};
        #pragma unroll
        for (int i = 0; i < 4; i++)
            #pragma unroll
            for (int j = 0; j < 8; j++) acc[i][j] += av[i] * wv[j];
    }
    __syncthreads();
    for (int i = 0; i < 32; i++) {
        int idx = t + i * 256;
        sW[idx >> 7][idx & 127] = rank_w[(size_t)(d0 + (idx >> 7)) * 128 + (idx & 127)];
    }
    for (int i = 0; i < 16; i++) {
        int idx = t + i * 256;
        int r = idx >> 6, d = idx & 63;
        int dgl = d0 + d;
        float irow = (float)(r0 + r);
        float val;
        if (dgl < 512) {
            float dm = exp2f(-(float)dgl * 0.019464422f);
            val = __sinf(irow * dm);
        } else {
            float dm = exp2f(-(float)(dgl - 512) * 0.019464422f);
            val = __cosf(irow * dm);
        }
        sAT[d][r] = val;
    }
    __syncthreads();
    for (int d = 0; d < 64; d++) {
        float4 a4 = *(float4*)&sAT[d][tr*4];
        float4 w0 = *(float4*)&sW[d][tc*8];
        float4 w1 = *(float4*)&sW[d][tc*8+4];
        float av[4] = {a4.x, a4.y, a4.z, a4.w};
        float wv[8] = {w0.x, w0.y, w0.z, w0.w, w1.x, w1.y, w1.z, w1.w};
        #pragma unroll
        for (int i = 0; i < 4; i++)
            #pragma unroll
            for (int j = 0; j < 8; j++) acc[i][j] += av[i] * wv[j];
    }
    for (int i = 0; i < 4; i++) {
        float* dst = &part[((size_t)dc * 1024 + r0 + tr*4 + i) * 128 + tc*8];
        *(float4*)dst       = make_float4(acc[i][0], acc[i][1], acc[i][2], acc[i][3]);
        *(float4*)(dst + 4) = make_float4(acc[i][4], acc[i][5], acc[i][6], acc[i][7]);
    }
}

// ---------------------------------------------------------------- k_embsum
__global__ void k_embsum(const float* __restrict__ part,
                         const float* __restrict__ feat_b, const float* __restrict__ rank_b,
                         float* __restrict__ emb)
{
    int gid = blockIdx.x * 256 + threadIdx.x;
    int c = gid & 127;
    float acc = feat_b[c] + rank_b[c];
    for (int dc = 0; dc < 16; dc++) acc += part[(size_t)dc * 131072 + gid];
    emb[gid] = acc;
}

// ---------------------------------------------------------------- k_qkv
__global__ void k_qkv(const float* __restrict__ emb,
                      const float* __restrict__ wq, const float* __restrict__ bq,
                      const float* __restrict__ wk, const float* __restrict__ bk,
                      const float* __restrict__ wv, const float* __restrict__ bv,
                      bf16* __restrict__ q, bf16* __restrict__ k, bf16* __restrict__ v)
{
    __shared__ float et[64][DF];
    int h = blockIdx.x, nt = blockIdx.y, t = threadIdx.x;
    int n0 = nt * 64;
    for (int idx = t; idx < 64 * DF; idx += 256) {
        int r = idx >> 7, c = idx & 127;
        et[r][c] = emb[(n0 + r) * DF + c];
    }
    __syncthreads();
    int kk = t & 63, g = t >> 6;
    const float* Ws[3] = { wq, wk, wv };
    const float* Bs[3] = { bq, bk, bv };
    bf16* Os[3] = { q, k, v };
    for (int m3 = 0; m3 < 3; m3++) {
        float bias = Bs[m3][h * DK + kk];
        float acc[16];
        #pragma unroll
        for (int ii = 0; ii < 16; ii++) acc[ii] = bias;
        for (int d = 0; d < DF; d++) {
            float w = Ws[m3][(h * DF + d) * DK + kk];
            #pragma unroll
            for (int ii = 0; ii < 16; ii++) acc[ii] += et[g*16 + ii][d] * w;
        }
        for (int ii = 0; ii < 16; ii++)
            Os[m3][((size_t)h * N + n0 + g*16 + ii) * DK + kk] = __float2bfloat16(acc[ii]);
    }
}

// ---------------------------------------------------------------- k_geo
__global__ void __launch_bounds__(256) k_geo(
        const float* __restrict__ sbbox, const float* __restrict__ wgw,
        const float* __restrict__ wgb, bf16* __restrict__ lw)
{
    __shared__ float sw[NH][64];
    __shared__ float sb[NH];
    __shared__ float mbb[4];
    int m = blockIdx.x, nc = blockIdx.y, t = threadIdx.x;
    for (int idx = t; idx < NH * 64; idx += 256) sw[idx >> 6][idx & 63] = wgw[idx];
    if (t < NH) sb[t] = wgb[t];
    if (t == 0) {
        float b0 = sbbox[m*4+0], b1 = sbbox[m*4+1], b2 = sbbox[m*4+2], b3 = sbbox[m*4+3];
        mbb[0] = (b0 + b2) * 0.5f; mbb[1] = (b1 + b3) * 0.5f;
        mbb[2] = b2 - b0 + 1.0f;   mbb[3] = b3 - b1 + 1.0f;
    }
    __syncthreads();
    int n = nc * 256 + t;
    float b0 = sbbox[n*4+0], b1 = sbbox[n*4+1], b2 = sbbox[n*4+2], b3 = sbbox[n*4+3];
    float cxn = (b0 + b2) * 0.5f, cyn = (b1 + b3) * 0.5f;
    float wn = b2 - b0 + 1.0f, hn = b3 - b1 + 1.0f;
    float dx = __logf(fmaxf(fabsf((mbb[0] - cxn) / mbb[2]), 1e-3f));
    float dy = __logf(fmaxf(fabsf((mbb[1] - cyn) / mbb[3]), 1e-3f));
    float dw = __logf(mbb[2] / wn);
    float dh = __logf(mbb[3] / hn);
    float pos[4] = { dx, dy, dw, dh };
    const float dmt[8] = { 1.0f, 0.42169650342f, 0.177827941f, 0.0749894209f,
                           0.0316227766f, 0.01333521432f, 0.00562341325f, 0.00237137371f };
    float emb[64];
    #pragma unroll
    for (int c = 0; c < 4; c++)
        #pragma unroll
        for (int f = 0; f < 8; f++) {
            float arg = 100.0f * pos[c] * dmt[f];
            emb[c*8 + f]      = __sinf(arg);
            emb[32 + c*8 + f] = __cosf(arg);
        }
    size_t base = ((size_t)m << 10) + n;
    #pragma unroll
    for (int hh = 0; hh < NH; hh++) {
        float wg = sb[hh];
        #pragma unroll
        for (int e = 0; e < 16; e++) {
            float4 w4 = *(float4*)&sw[hh][e*4];
            wg += emb[e*4]*w4.x + emb[e*4+1]*w4.y + emb[e*4+2]*w4.z + emb[e*4+3]*w4.w;
        }
        wg = fmaxf(wg, 0.f);
        lw[((size_t)hh << 20) + base] = __float2bfloat16(__logf(fmaxf(wg, 1e-6f)));
    }
}

// ---------------------------------------------------------------- k_attn3 (MFMA flash)
// Block = (64-row m-tile, head). 4 waves, wave owns 16 rows.
// S = K.Q^T/8 + lw; online softmax over n; O = P.V / Z.
__global__ void __launch_bounds__(256) k_attn3(
        const bf16* __restrict__ q, const bf16* __restrict__ kmat,
        const bf16* __restrict__ v, const bf16* __restrict__ lw,
        bf16* __restrict__ rel)
{
    // rows padded to 36 uints: 144B row stride -> 16B-aligned ds_read_b128,
    // start bank = (4*(row+quad)) % 32 -> 2-way max (free per m136)
    __shared__ uint sQu[64][36];       // Q tile, [n][k/2]
    __shared__ uint sVtu[64][36];      // V transposed, [kv][n/2] (n-pairs packed)
    __shared__ uint slwu[64][36];      // lw tile, [m_local][n/2]
    __shared__ uint sPu[4][16][36];    // P per wave, [m_local16][n/2] bf16 pairs

    int t = threadIdx.x;
    int mt = blockIdx.x, h = blockIdx.y;
    int m0 = mt * 64;
    int w = t >> 6, l = t & 63, l15 = l & 15, quad = l >> 4;

    // K fragments resident in registers (A-operand layout: A[m=l15][k=quad*8+j])
    U4S8 kf0, kf1;
    {
        const uint4* k4 = (const uint4*)kmat;   // 8 bf16 per uint4; row = 8 uint4
        size_t krow = ((size_t)h * N + m0 + w*16 + l15) * 8;
        kf0.u = k4[krow + quad];
        kf1.u = k4[krow + 4 + quad];
    }

    float4v O[4];
    float M[4], Z[4];
    #pragma unroll
    for (int i = 0; i < 4; i++) {
        O[i] = (float4v){0.f, 0.f, 0.f, 0.f};
        M[i] = -1e30f; Z[i] = 0.f;
    }

    const uint* qsrc = (const uint*)q;
    const uint* vsrc = (const uint*)v;
    const uint* lwsrc = (const uint*)lw;

    for (int tile = 0; tile < 16; tile++) {
        int n0 = tile * 64;
        // ---- cooperative loads
        #pragma unroll
        for (int i = 0; i < 8; i++) {            // Q: 2048 uints
            int idx = t + i * 256;
            int nj = idx >> 5, kp = idx & 31;
            sQu[nj][kp] = qsrc[((size_t)h * N + n0 + nj) * 32 + kp];
        }
        #pragma unroll
        for (int i = 0; i < 4; i++) {            // V transposed: 1024 work items
            int idx = t + i * 256;
            int a = idx & 31, nh = idx >> 5;     // kv-pair, n-pair
            uint g0 = vsrc[((size_t)h * N + n0 + 2*nh) * 32 + a];
            uint g1 = vsrc[((size_t)h * N + n0 + 2*nh + 1) * 32 + a];
            sVtu[2*a][nh]     = (g0 & 0xFFFFu) | (g1 << 16);
            sVtu[2*a + 1][nh] = (g0 >> 16) | (g1 & 0xFFFF0000u);
        }
        #pragma unroll
        for (int i = 0; i < 8; i++) {            // lw tile: 2048 uints
            int idx = t + i * 256;
            int mi = idx >> 5, np = idx & 31;
            slwu[mi][np] = lwsrc[((size_t)h << 19) + ((size_t)(m0 + mi) << 9) + (n0 >> 1) + np];
        }
        __syncthreads();

        // ---- QK^T (8 MFMAs) -> C-layout S[nb][reg]: row=quad*4+reg, col=l15+16nb
        float4v S[4];
        #pragma unroll
        for (int nb = 0; nb < 4; nb++) {
            U4S8 bq0, bq1;
            bq0.u = *(uint4*)&sQu[nb*16 + l15][quad*4];
            bq1.u = *(uint4*)&sQu[nb*16 + l15][16 + quad*4];
            float4v zz = (float4v){0.f, 0.f, 0.f, 0.f};
            float4v p0 = __builtin_amdgcn_mfma_f32_16x16x32_bf16(kf0.s, bq0.s, zz, 0, 0, 0);
            S[nb] = __builtin_amdgcn_mfma_f32_16x16x32_bf16(kf1.s, bq1.s, p0, 0, 0, 0);
        }
        // ---- add lw, online softmax per row r (row = quad*4 + r)
        ushort* pRow[4];
        #pragma unroll
        for (int r = 0; r < 4; r++) pRow[r] = (ushort*)&sPu[w][quad*4 + r][0];
        #pragma unroll
        for (int r = 0; r < 4; r++) {
            int mi = w*16 + quad*4 + r;
            float sv[4];
            #pragma unroll
            for (int nb = 0; nb < 4; nb++) {
                int col = nb*16 + l15;
                uint lu = slwu[mi][col >> 1];
                float lv = (col & 1) ? __uint_as_float(lu & 0xFFFF0000u)
                                     : __uint_as_float(lu << 16);
                sv[nb] = S[nb][r] * 0.125f + lv;
            }
            float rm = fmaxf(fmaxf(sv[0], sv[1]), fmaxf(sv[2], sv[3]));
            #pragma unroll
            for (int off = 1; off < 16; off <<= 1)
                rm = fmaxf(rm, __shfl_xor(rm, off, 64));
            float newM = fmaxf(M[r], rm);
            float pr[4], rs = 0.f;
            #pragma unroll
            for (int nb = 0; nb < 4; nb++) {
                pr[nb] = __expf(sv[nb] - newM);
                rs += pr[nb];
            }
            #pragma unroll
            for (int off = 1; off < 16; off <<= 1)
                rs += __shfl_xor(rs, off, 64);
            float sc = __expf(M[r] - newM);
            M[r] = newM;
            Z[r] = Z[r] * sc + rs;
            #pragma unroll
            for (int kvb = 0; kvb < 4; kvb++) O[kvb][r] *= sc;
            #pragma unroll
            for (int nb = 0; nb < 4; nb++)
                pRow[r][nb*16 + l15] = f2bu(pr[nb]);
        }
        // same-wave LDS RAW (compiler inserts lgkmcnt waits) — no barrier needed
        // ---- PV (8 MFMAs): A = P (A[m=l15][n=quad*8+j]), B = V^T
        {
            U4S8 ap0, ap1;
            ap0.u = *(uint4*)&sPu[w][l15][quad*4];
            ap1.u = *(uint4*)&sPu[w][l15][16 + quad*4];
            #pragma unroll
            for (int kvb = 0; kvb < 4; kvb++) {
                U4S8 bv0, bv1;
                bv0.u = *(uint4*)&sVtu[kvb*16 + l15][quad*4];
                bv1.u = *(uint4*)&sVtu[kvb*16 + l15][16 + quad*4];
                O[kvb] = __builtin_amdgcn_mfma_f32_16x16x32_bf16(ap0.s, bv0.s, O[kvb], 0, 0, 0);
                O[kvb] = __builtin_amdgcn_mfma_f32_16x16x32_bf16(ap1.s, bv1.s, O[kvb], 0, 0, 0);
            }
        }
        __syncthreads();   // protect sQu/sVtu/slwu before next tile's loads
    }

    // ---- epilogue: rel[h][m][kv] = O / Z
    float invZ[4];
    #pragma unroll
    for (int r = 0; r < 4; r++) invZ[r] = 1.0f / Z[r];
    ushort* relu = (ushort*)rel;
    #pragma unroll
    for (int r = 0; r < 4; r++) {
        size_t mrow = ((size_t)h * N + m0 + w*16 + quad*4 + r) * 64;
        #pragma unroll
        for (int kvb = 0; kvb < 4; kvb++)
            relu[mrow + kvb*16 + l15] = f2bu(O[kvb][r] * invZ[r]);
    }
}

// ---------------------------------------------------------------- k_final
__global__ void k_final(const bf16* __restrict__ rel, const int* __restrict__ order,
                        const float* __restrict__ app, const float* __restrict__ lw,
                        const float* __restrict__ lb, const float* __restrict__ sprob,
                        float* __restrict__ out)
{
    __shared__ float red[2];
    int m = blockIdx.x, t = threadIdx.x;
    int o = order[m];
    float s = 0.f;
    for (int j = t; j < APP; j += 128) {
        int hh = j >> 6, kk = j & 63;
        float rv = b2f(rel[((size_t)hh * N + m) * DK + kk]) + app[o * APP + j];
        s += rv * lw[j];
    }
    #pragma unroll
    for (int off = 32; off > 0; off >>= 1) s += __shfl_down(s, off, 64);
    if ((t & 63) == 0) red[t >> 6] = s;
    __syncthreads();
    if (t == 0) {
        float tot = red[0] + red[1] + lb[0];
        float s1 = 1.0f / (1.0f + expf(-tot));
        out[m] = s1 * sprob[m];
    }
}

// ---------------------------------------------------------------- launch
extern "C" void kernel_launch(void* const* d_in, const int* in_sizes, int n_in,
                              void* d_out, int out_size, void* d_ws, size_t ws_size,
                              hipStream_t stream)
{
    const float* roi      = (const float*)d_in[0];
    const float* cls_loc  = (const float*)d_in[1];
    const float* score    = (const float*)d_in[2];
    const float* app      = (const float*)d_in[3];
    const int*   size     = (const int*)d_in[4];
    const float* rank_w   = (const float*)d_in[5];
    const float* rank_b   = (const float*)d_in[6];
    const float* feat_w   = (const float*)d_in[7];
    const float* feat_b   = (const float*)d_in[8];
    const float* logit_w  = (const float*)d_in[9];
    const float* logit_b  = (const float*)d_in[10];
    const float* wg_w     = (const float*)d_in[11];
    const float* wg_b     = (const float*)d_in[12];
    const float* wk_w     = (const float*)d_in[13];
    const float* wk_b     = (const float*)d_in[14];
    const float* wq_w     = (const float*)d_in[15];
    const float* wq_b     = (const float*)d_in[16];
    const float* wv_w     = (const float*)d_in[17];
    const float* wv_b     = (const float*)d_in[18];
    float* out = (float*)d_out;

    char* ws = (char*)d_ws;
    float* prob  = (float*)(ws + 0);
    int*   label = (int*)  (ws + 4096);
    float* bbox  = (float*)(ws + 8192);
    u64*   keys  = (u64*)  (ws + 24576);
    int*   order = (int*)  (ws + 32768);
    float* sprob = (float*)(ws + 36864);
    float* sbbox = (float*)(ws + 40960);
    float* emb   = (float*)(ws + 57344);      // 512 KB
    float* part  = (float*)(ws + 581632);     // 8 MB
    bf16*  q     = (bf16*) (ws + 8970240);    // 2 MB
    bf16*  k     = (bf16*) (ws + 11067392);   // 2 MB
    bf16*  v     = (bf16*) (ws + 13164544);   // 2 MB
    bf16*  rel   = (bf16*) (ws + 15261696);   // 2 MB
    bf16*  lwbuf = (bf16*) (ws + 17358848);   // 32 MB

    k_prep<<<4, 256, 0, stream>>>(roi, cls_loc, score, size, prob, label, bbox, keys);
    k_sort<<<1, 1024, 0, stream>>>(keys, prob, label, bbox, order, sprob, sbbox, out);
    k_emb<<<dim3(16, 16), 256, 0, stream>>>(order, app, feat_w, rank_w, part);
    k_embsum<<<512, 256, 0, stream>>>(part, feat_b, rank_b, emb);
    k_qkv<<<dim3(16, 16), 256, 0, stream>>>(emb, wq_w, wq_b, wk_w, wk_b, wv_w, wv_b, q, k, v);
    k_geo<<<dim3(1024, 4), 256, 0, stream>>>(sbbox, wg_w, wg_b, lwbuf);
    k_attn3<<<dim3(16, 16), 256, 0, stream>>>(q, k, v, lwbuf, rel);
    k_final<<<1024, 128, 0, stream>>>(rel, order, app, logit_w, logit_b, sprob, out);
}

// Round 7
// 215.554 us; speedup vs baseline: 3.1128x; 1.1811x over previous
//
#include <hip/hip_runtime.h>
#include <hip/hip_bf16.h>
#include <math.h>

typedef unsigned long long u64;
typedef unsigned int u32;
typedef __hip_bfloat16 bf16;

#define N 1024
#define NCLS 21
#define APP 1024
#define DF 128
#define NH 16
#define DK 64

typedef __attribute__((ext_vector_type(8))) short short8v;
typedef __attribute__((ext_vector_type(4))) float float4v;
union U4S8 { uint4 u; short8v s; };

__device__ __forceinline__ float b2f(bf16 x) { return __bfloat162float(x); }
__device__ __forceinline__ ushort f2bu(float x) { bf16 b = __float2bfloat16(x); return *(ushort*)&b; }

// ---------------------------------------------------------------- k_prep
__global__ void k_prep(const float* __restrict__ roi, const float* __restrict__ cls_loc,
                       const float* __restrict__ score, const int* __restrict__ size,
                       float* __restrict__ prob, int* __restrict__ label,
                       float* __restrict__ bbox, u64* __restrict__ keys)
{
    int i = blockIdx.x * 256 + threadIdx.x;
    if (i >= N) return;
    float s[NCLS];
    float mx = -1e30f; int am = 0;
    for (int c = 0; c < NCLS; c++) {
        s[c] = score[i * NCLS + c];
        if (s[c] > mx) { mx = s[c]; am = c; }
    }
    float sum = 0.f;
    for (int c = 0; c < NCLS; c++) sum += expf(s[c] - mx);
    float p = 1.0f / sum;

    float y0 = roi[i*4+0], x0 = roi[i*4+1];
    float y1 = roi[i*4+2], x1 = roi[i*4+3];
    float hh = y1 - y0, ww = x1 - x0;
    float cy = y0 + 0.5f * hh, cx = x0 + 0.5f * ww;
    float l0 = cls_loc[i*84 + am*4 + 0] * 0.1f;
    float l1 = cls_loc[i*84 + am*4 + 1] * 0.1f;
    float l2 = cls_loc[i*84 + am*4 + 2] * 0.2f;
    float l3 = cls_loc[i*84 + am*4 + 3] * 0.2f;
    float ncy = l0 * hh + cy, ncx = l1 * ww + cx;
    float nh = expf(l2) * hh, nw = expf(l3) * ww;
    float b0 = ncy - 0.5f * nh, b1 = ncx - 0.5f * nw;
    float b2v = ncy + 0.5f * nh, b3 = ncx + 0.5f * nw;
    float lim = ((am & 1) == 0) ? (float)size[0] : (float)size[1];
    b0  = fminf(fmaxf(b0, 0.f), lim);
    b1  = fminf(fmaxf(b1, 0.f), lim);
    b2v = fminf(fmaxf(b2v, 0.f), lim);
    b3  = fminf(fmaxf(b3, 0.f), lim);
    prob[i] = p; label[i] = am;
    bbox[i*4+0] = b0; bbox[i*4+1] = b1; bbox[i*4+2] = b2v; bbox[i*4+3] = b3;
    keys[i] = ((u64)(0xFFFFFFFFu - __float_as_uint(p)) << 32) | (u32)i;
}

// ---------------------------------------------------------------- k_sort
__global__ void __launch_bounds__(1024) k_sort(
        const u64* __restrict__ keys, const float* __restrict__ prob,
        const int* __restrict__ label, const float* __restrict__ bbox,
        int* __restrict__ order, float* __restrict__ sprob,
        float* __restrict__ sbbox, float* __restrict__ out)
{
    __shared__ u64 sk[N];
    int t = threadIdx.x;
    sk[t] = keys[t];
    __syncthreads();
    for (int k = 2; k <= N; k <<= 1) {
        for (int j = k >> 1; j > 0; j >>= 1) {
            int p = t ^ j;
            if (p > t) {
                u64 a = sk[t], b = sk[p];
                bool up = ((t & k) == 0);
                if ((a > b) == up) { sk[t] = b; sk[p] = a; }
            }
            __syncthreads();
        }
    }
    int o = (int)(sk[t] & 0xFFFFFFFFull);
    order[t] = o;
    sprob[t] = prob[o];
    float b0 = bbox[o*4+0], b1 = bbox[o*4+1], b2 = bbox[o*4+2], b3 = bbox[o*4+3];
    sbbox[t*4+0] = b0; sbbox[t*4+1] = b1; sbbox[t*4+2] = b2; sbbox[t*4+3] = b3;
    out[N + t] = (float)(label[o] - 1);
    out[2*N + t*4 + 0] = b0;
    out[2*N + t*4 + 1] = b1;
    out[2*N + t*4 + 2] = b2;
    out[2*N + t*4 + 3] = b3;
}

// ---------------------------------------------------------------- k_emb (split-K partials)
__global__ void __launch_bounds__(256) k_emb(
        const int* __restrict__ order, const float* __restrict__ app,
        const float* __restrict__ feat_w, const float* __restrict__ rank_w,
        float* __restrict__ part)
{
    __shared__ float sAT[64][68];
    __shared__ float sW[64][128];
    __shared__ int sOrd[64];
    int rt = blockIdx.x, dc = blockIdx.y, t = threadIdx.x;
    int r0 = rt * 64, d0 = dc * 64;
    if (t < 64) sOrd[t] = order[r0 + t];
    __syncthreads();
    for (int i = 0; i < 32; i++) {
        int idx = t + i * 256;
        sW[idx >> 7][idx & 127] = feat_w[(size_t)(d0 + (idx >> 7)) * 128 + (idx & 127)];
    }
    for (int i = 0; i < 16; i++) {
        int idx = t + i * 256;
        int r = idx >> 6, d = idx & 63;
        sAT[d][r] = app[(size_t)sOrd[r] * 1024 + d0 + d];
    }
    __syncthreads();
    int tr = t >> 4, tc = t & 15;
    float acc[4][8];
    #pragma unroll
    for (int i = 0; i < 4; i++)
        #pragma unroll
        for (int j = 0; j < 8; j++) acc[i][j] = 0.f;
    for (int d = 0; d < 64; d++) {
        float4 a4 = *(float4*)&sAT[d][tr*4];
        float4 w0 = *(float4*)&sW[d][tc*8];
        float4 w1 = *(float4*)&sW[d][tc*8+4];
        float av[4] = {a4.x, a4.y, a4.z, a4.w};
        float wv[8] = {w0.x, w0.y, w0.z, w0.w, w1.x, w1.y, w1.z, w1.w};
        #pragma unroll
        for (int i = 0; i < 4; i++)
            #pragma unroll
            for (int j = 0; j < 8; j++) acc[i][j] += av[i] * wv[j];
    }
    __syncthreads();
    for (int i = 0; i < 32; i++) {
        int idx = t + i * 256;
        sW[idx >> 7][idx & 127] = rank_w[(size_t)(d0 + (idx >> 7)) * 128 + (idx & 127)];
    }
    for (int i = 0; i < 16; i++) {
        int idx = t + i * 256;
        int r = idx >> 6, d = idx & 63;
        int dgl = d0 + d;
        float irow = (float)(r0 + r);
        float val;
        if (dgl < 512) {
            float dm = exp2f(-(float)dgl * 0.019464422f);
            val = __sinf(irow * dm);
        } else {
            float dm = exp2f(-(float)(dgl - 512) * 0.019464422f);
            val = __cosf(irow * dm);
        }
        sAT[d][r] = val;
    }
    __syncthreads();
    for (int d = 0; d < 64; d++) {
        float4 a4 = *(float4*)&sAT[d][tr*4];
        float4 w0 = *(float4*)&sW[d][tc*8];
        float4 w1 = *(float4*)&sW[d][tc*8+4];
        float av[4] = {a4.x, a4.y, a4.z, a4.w};
        float wv[8] = {w0.x, w0.y, w0.z, w0.w, w1.x, w1.y, w1.z, w1.w};
        #pragma unroll
        for (int i = 0; i < 4; i++)
            #pragma unroll
            for (int j = 0; j < 8; j++) acc[i][j] += av[i] * wv[j];
    }
    for (int i = 0; i < 4; i++) {
        float* dst = &part[((size_t)dc * 1024 + r0 + tr*4 + i) * 128 + tc*8];
        *(float4*)dst       = make_float4(acc[i][0], acc[i][1], acc[i][2], acc[i][3]);
        *(float4*)(dst + 4) = make_float4(acc[i][4], acc[i][5], acc[i][6], acc[i][7]);
    }
}

// ---------------------------------------------------------------- k_embsum (-> bf16)
__global__ void k_embsum(const float* __restrict__ part,
                         const float* __restrict__ feat_b, const float* __restrict__ rank_b,
                         bf16* __restrict__ embb)
{
    int gid = blockIdx.x * 256 + threadIdx.x;
    int c = gid & 127;
    float acc = feat_b[c] + rank_b[c];
    for (int dc = 0; dc < 16; dc++) acc += part[(size_t)dc * 131072 + gid];
    embb[gid] = __float2bfloat16(acc);
}

// ---------------------------------------------------------------- k_qkv2 (MFMA)
// out[h,n,kk] = emb_bf[n,:]@W[h,:,kk] + b[h,kk]; block = (row-tile, head, mat)
__global__ void __launch_bounds__(256) k_qkv2(
        const bf16* __restrict__ embb,
        const float* __restrict__ wq, const float* __restrict__ bq,
        const float* __restrict__ wk, const float* __restrict__ bk,
        const float* __restrict__ wv, const float* __restrict__ bv,
        bf16* __restrict__ q, bf16* __restrict__ k, bf16* __restrict__ v)
{
    __shared__ ushort sWt[64][136];   // W^T bf16: [kk][d], pitch 136 -> 16B aligned rows
    int t = threadIdx.x;
    int rt = blockIdx.x, h = blockIdx.y, mat = blockIdx.z;
    const float* W  = (mat == 0) ? wq : (mat == 1) ? wk : wv;
    const float* Bb = (mat == 0) ? bq : (mat == 1) ? bk : bv;
    bf16* Out       = (mat == 0) ? q  : (mat == 1) ? k  : v;

    #pragma unroll
    for (int i = 0; i < 32; i++) {
        int idx = t + i * 256;
        int d = idx >> 6, kk = idx & 63;
        sWt[kk][d] = f2bu(W[((size_t)h * 128 + d) * 64 + kk]);
    }
    int w = t >> 6, l = t & 63, l15 = l & 15, quad = l >> 4;
    float biasv[4];
    #pragma unroll
    for (int nb = 0; nb < 4; nb++) biasv[nb] = Bb[h * 64 + nb*16 + l15];
    __syncthreads();

    // B-fragments resident: B[k=quad*8+j][n=l15+16nb], k-chunk kc
    U4S8 Bf[4][4];
    #pragma unroll
    for (int nb = 0; nb < 4; nb++)
        #pragma unroll
        for (int kc = 0; kc < 4; kc++)
            Bf[nb][kc].u = *(uint4*)&sWt[nb*16 + l15][kc*32 + quad*8];

    const uint4* A4 = (const uint4*)embb;     // 8 bf16 per uint4; row = 16 uint4
    int r0 = rt * 256 + w * 64;
    ushort* outu = (ushort*)Out;
    for (int mb = 0; mb < 4; mb++) {
        int arow = r0 + mb*16 + l15;
        U4S8 Af[4];
        #pragma unroll
        for (int kc = 0; kc < 4; kc++) Af[kc].u = A4[(size_t)arow * 16 + kc*4 + quad];
        float4v acc[4];
        #pragma unroll
        for (int nb = 0; nb < 4; nb++) acc[nb] = (float4v){0.f, 0.f, 0.f, 0.f};
        #pragma unroll
        for (int kc = 0; kc < 4; kc++)
            #pragma unroll
            for (int nb = 0; nb < 4; nb++)
                acc[nb] = __builtin_amdgcn_mfma_f32_16x16x32_bf16(Af[kc].s, Bf[nb][kc].s, acc[nb], 0, 0, 0);
        #pragma unroll
        for (int reg = 0; reg < 4; reg++) {
            int orow = r0 + mb*16 + quad*4 + reg;
            #pragma unroll
            for (int nb = 0; nb < 4; nb++)
                outu[((size_t)h * N + orow) * 64 + nb*16 + l15] = f2bu(acc[nb][reg] + biasv[nb]);
        }
    }
}

// ---------------------------------------------------------------- k_geo
__global__ void __launch_bounds__(256) k_geo(
        const float* __restrict__ sbbox, const float* __restrict__ wgw,
        const float* __restrict__ wgb, bf16* __restrict__ lw)
{
    __shared__ float sw[NH][64];
    __shared__ float sb[NH];
    __shared__ float mbb[4];
    int m = blockIdx.x, nc = blockIdx.y, t = threadIdx.x;
    for (int idx = t; idx < NH * 64; idx += 256) sw[idx >> 6][idx & 63] = wgw[idx];
    if (t < NH) sb[t] = wgb[t];
    if (t == 0) {
        float b0 = sbbox[m*4+0], b1 = sbbox[m*4+1], b2 = sbbox[m*4+2], b3 = sbbox[m*4+3];
        mbb[0] = (b0 + b2) * 0.5f; mbb[1] = (b1 + b3) * 0.5f;
        mbb[2] = b2 - b0 + 1.0f;   mbb[3] = b3 - b1 + 1.0f;
    }
    __syncthreads();
    int n = nc * 256 + t;
    float b0 = sbbox[n*4+0], b1 = sbbox[n*4+1], b2 = sbbox[n*4+2], b3 = sbbox[n*4+3];
    float cxn = (b0 + b2) * 0.5f, cyn = (b1 + b3) * 0.5f;
    float wn = b2 - b0 + 1.0f, hn = b3 - b1 + 1.0f;
    float dx = __logf(fmaxf(fabsf((mbb[0] - cxn) / mbb[2]), 1e-3f));
    float dy = __logf(fmaxf(fabsf((mbb[1] - cyn) / mbb[3]), 1e-3f));
    float dw = __logf(mbb[2] / wn);
    float dh = __logf(mbb[3] / hn);
    float pos[4] = { dx, dy, dw, dh };
    const float dmt[8] = { 1.0f, 0.42169650342f, 0.177827941f, 0.0749894209f,
                           0.0316227766f, 0.01333521432f, 0.00562341325f, 0.00237137371f };
    float emb[64];
    #pragma unroll
    for (int c = 0; c < 4; c++)
        #pragma unroll
        for (int f = 0; f < 8; f++) {
            float arg = 100.0f * pos[c] * dmt[f];
            emb[c*8 + f]      = __sinf(arg);
            emb[32 + c*8 + f] = __cosf(arg);
        }
    size_t base = ((size_t)m << 10) + n;
    #pragma unroll
    for (int hh = 0; hh < NH; hh++) {
        float wg = sb[hh];
        #pragma unroll
        for (int e = 0; e < 16; e++) {
            float4 w4 = *(float4*)&sw[hh][e*4];
            wg += emb[e*4]*w4.x + emb[e*4+1]*w4.y + emb[e*4+2]*w4.z + emb[e*4+3]*w4.w;
        }
        wg = fmaxf(wg, 0.f);
        lw[((size_t)hh << 20) + base] = __float2bfloat16(__logf(fmaxf(wg, 1e-6f)));
    }
}

// ---------------------------------------------------------------- k_attn3 (MFMA flash)
__global__ void __launch_bounds__(256) k_attn3(
        const bf16* __restrict__ q, const bf16* __restrict__ kmat,
        const bf16* __restrict__ v, const bf16* __restrict__ lw,
        bf16* __restrict__ rel)
{
    __shared__ uint sQu[64][36];
    __shared__ uint sVtu[64][36];
    __shared__ uint slwu[64][36];
    __shared__ uint sPu[4][16][36];

    int t = threadIdx.x;
    int mt = blockIdx.x, h = blockIdx.y;
    int m0 = mt * 64;
    int w = t >> 6, l = t & 63, l15 = l & 15, quad = l >> 4;

    U4S8 kf0, kf1;
    {
        const uint4* k4 = (const uint4*)kmat;
        size_t krow = ((size_t)h * N + m0 + w*16 + l15) * 8;
        kf0.u = k4[krow + quad];
        kf1.u = k4[krow + 4 + quad];
    }

    float4v O[4];
    float M[4], Z[4];
    #pragma unroll
    for (int i = 0; i < 4; i++) {
        O[i] = (float4v){0.f, 0.f, 0.f, 0.f};
        M[i] = -1e30f; Z[i] = 0.f;
    }

    const uint* qsrc = (const uint*)q;
    const uint* vsrc = (const uint*)v;
    const uint* lwsrc = (const uint*)lw;

    for (int tile = 0; tile < 16; tile++) {
        int n0 = tile * 64;
        #pragma unroll
        for (int i = 0; i < 8; i++) {
            int idx = t + i * 256;
            int nj = idx >> 5, kp = idx & 31;
            sQu[nj][kp] = qsrc[((size_t)h * N + n0 + nj) * 32 + kp];
        }
        #pragma unroll
        for (int i = 0; i < 4; i++) {
            int idx = t + i * 256;
            int a = idx & 31, nh2 = idx >> 5;
            uint g0 = vsrc[((size_t)h * N + n0 + 2*nh2) * 32 + a];
            uint g1 = vsrc[((size_t)h * N + n0 + 2*nh2 + 1) * 32 + a];
            sVtu[2*a][nh2]     = (g0 & 0xFFFFu) | (g1 << 16);
            sVtu[2*a + 1][nh2] = (g0 >> 16) | (g1 & 0xFFFF0000u);
        }
        #pragma unroll
        for (int i = 0; i < 8; i++) {
            int idx = t + i * 256;
            int mi = idx >> 5, np = idx & 31;
            slwu[mi][np] = lwsrc[((size_t)h << 19) + ((size_t)(m0 + mi) << 9) + (n0 >> 1) + np];
        }
        __syncthreads();

        float4v S[4];
        #pragma unroll
        for (int nb = 0; nb < 4; nb++) {
            U4S8 bq0, bq1;
            bq0.u = *(uint4*)&sQu[nb*16 + l15][quad*4];
            bq1.u = *(uint4*)&sQu[nb*16 + l15][16 + quad*4];
            float4v zz = (float4v){0.f, 0.f, 0.f, 0.f};
            float4v p0 = __builtin_amdgcn_mfma_f32_16x16x32_bf16(kf0.s, bq0.s, zz, 0, 0, 0);
            S[nb] = __builtin_amdgcn_mfma_f32_16x16x32_bf16(kf1.s, bq1.s, p0, 0, 0, 0);
        }
        ushort* pRow[4];
        #pragma unroll
        for (int r = 0; r < 4; r++) pRow[r] = (ushort*)&sPu[w][quad*4 + r][0];
        #pragma unroll
        for (int r = 0; r < 4; r++) {
            int mi = w*16 + quad*4 + r;
            float sv[4];
            #pragma unroll
            for (int nb = 0; nb < 4; nb++) {
                int col = nb*16 + l15;
                uint lu = slwu[mi][col >> 1];
                float lv = (col & 1) ? __uint_as_float(lu & 0xFFFF0000u)
                                     : __uint_as_float(lu << 16);
                sv[nb] = S[nb][r] * 0.125f + lv;
            }
            float rm = fmaxf(fmaxf(sv[0], sv[1]), fmaxf(sv[2], sv[3]));
            #pragma unroll
            for (int off = 1; off < 16; off <<= 1)
                rm = fmaxf(rm, __shfl_xor(rm, off, 64));
            float newM = fmaxf(M[r], rm);
            float pr[4], rs = 0.f;
            #pragma unroll
            for (int nb = 0; nb < 4; nb++) {
                pr[nb] = __expf(sv[nb] - newM);
                rs += pr[nb];
            }
            #pragma unroll
            for (int off = 1; off < 16; off <<= 1)
                rs += __shfl_xor(rs, off, 64);
            float sc = __expf(M[r] - newM);
            M[r] = newM;
            Z[r] = Z[r] * sc + rs;
            #pragma unroll
            for (int kvb = 0; kvb < 4; kvb++) O[kvb][r] *= sc;
            #pragma unroll
            for (int nb = 0; nb < 4; nb++)
                pRow[r][nb*16 + l15] = f2bu(pr[nb]);
        }
        {
            U4S8 ap0, ap1;
            ap0.u = *(uint4*)&sPu[w][l15][quad*4];
            ap1.u = *(uint4*)&sPu[w][l15][16 + quad*4];
            #pragma unroll
            for (int kvb = 0; kvb < 4; kvb++) {
                U4S8 bv0, bv1;
                bv0.u = *(uint4*)&sVtu[kvb*16 + l15][quad*4];
                bv1.u = *(uint4*)&sVtu[kvb*16 + l15][16 + quad*4];
                O[kvb] = __builtin_amdgcn_mfma_f32_16x16x32_bf16(ap0.s, bv0.s, O[kvb], 0, 0, 0);
                O[kvb] = __builtin_amdgcn_mfma_f32_16x16x32_bf16(ap1.s, bv1.s, O[kvb], 0, 0, 0);
            }
        }
        __syncthreads();
    }

    float invZ[4];
    #pragma unroll
    for (int r = 0; r < 4; r++) invZ[r] = 1.0f / Z[r];
    ushort* relu = (ushort*)rel;
    #pragma unroll
    for (int r = 0; r < 4; r++) {
        size_t mrow = ((size_t)h * N + m0 + w*16 + quad*4 + r) * 64;
        #pragma unroll
        for (int kvb = 0; kvb < 4; kvb++)
            relu[mrow + kvb*16 + l15] = f2bu(O[kvb][r] * invZ[r]);
    }
}

// ---------------------------------------------------------------- k_final
__global__ void k_final(const bf16* __restrict__ rel, const int* __restrict__ order,
                        const float* __restrict__ app, const float* __restrict__ lw,
                        const float* __restrict__ lb, const float* __restrict__ sprob,
                        float* __restrict__ out)
{
    __shared__ float red[2];
    int m = blockIdx.x, t = threadIdx.x;
    int o = order[m];
    float s = 0.f;
    for (int j = t; j < APP; j += 128) {
        int hh = j >> 6, kk = j & 63;
        float rv = b2f(rel[((size_t)hh * N + m) * DK + kk]) + app[o * APP + j];
        s += rv * lw[j];
    }
    #pragma unroll
    for (int off = 32; off > 0; off >>= 1) s += __shfl_down(s, off, 64);
    if ((t & 63) == 0) red[t >> 6] = s;
    __syncthreads();
    if (t == 0) {
        float tot = red[0] + red[1] + lb[0];
        float s1 = 1.0f / (1.0f + expf(-tot));
        out[m] = s1 * sprob[m];
    }
}

// ---------------------------------------------------------------- launch
extern "C" void kernel_launch(void* const* d_in, const int* in_sizes, int n_in,
                              void* d_out, int out_size, void* d_ws, size_t ws_size,
                              hipStream_t stream)
{
    const float* roi      = (const float*)d_in[0];
    const float* cls_loc  = (const float*)d_in[1];
    const float* score    = (const float*)d_in[2];
    const float* app      = (const float*)d_in[3];
    const int*   size     = (const int*)d_in[4];
    const float* rank_w   = (const float*)d_in[5];
    const float* rank_b   = (const float*)d_in[6];
    const float* feat_w   = (const float*)d_in[7];
    const float* feat_b   = (const float*)d_in[8];
    const float* logit_w  = (const float*)d_in[9];
    const float* logit_b  = (const float*)d_in[10];
    const float* wg_w     = (const float*)d_in[11];
    const float* wg_b     = (const float*)d_in[12];
    const float* wk_w     = (const float*)d_in[13];
    const float* wk_b     = (const float*)d_in[14];
    const float* wq_w     = (const float*)d_in[15];
    const float* wq_b     = (const float*)d_in[16];
    const float* wv_w     = (const float*)d_in[17];
    const float* wv_b     = (const float*)d_in[18];
    float* out = (float*)d_out;

    char* ws = (char*)d_ws;
    float* prob  = (float*)(ws + 0);
    int*   label = (int*)  (ws + 4096);
    float* bbox  = (float*)(ws + 8192);
    u64*   keys  = (u64*)  (ws + 24576);
    int*   order = (int*)  (ws + 32768);
    float* sprob = (float*)(ws + 36864);
    float* sbbox = (float*)(ws + 40960);
    bf16*  embb  = (bf16*) (ws + 57344);      // 256 KB bf16 emb
    float* part  = (float*)(ws + 581632);     // 8 MB
    bf16*  q     = (bf16*) (ws + 8970240);    // 2 MB
    bf16*  k     = (bf16*) (ws + 11067392);   // 2 MB
    bf16*  v     = (bf16*) (ws + 13164544);   // 2 MB
    bf16*  rel   = (bf16*) (ws + 15261696);   // 2 MB
    bf16*  lwbuf = (bf16*) (ws + 17358848);   // 32 MB

    k_prep<<<4, 256, 0, stream>>>(roi, cls_loc, score, size, prob, label, bbox, keys);
    k_sort<<<1, 1024, 0, stream>>>(keys, prob, label, bbox, order, sprob, sbbox, out);
    k_emb<<<dim3(16, 16), 256, 0, stream>>>(order, app, feat_w, rank_w, part);
    k_embsum<<<512, 256, 0, stream>>>(part, feat_b, rank_b, embb);
    k_qkv2<<<dim3(4, 16, 3), 256, 0, stream>>>(embb, wq_w, wq_b, wk_w, wk_b, wv_w, wv_b, q, k, v);
    k_geo<<<dim3(1024, 4), 256, 0, stream>>>(sbbox, wg_w, wg_b, lwbuf);
    k_attn3<<<dim3(16, 16), 256, 0, stream>>>(q, k, v, lwbuf, rel);
    k_final<<<1024, 128, 0, stream>>>(rel, order, app, logit_w, logit_b, sprob, out);
}

// Round 8
// 192.530 us; speedup vs baseline: 3.4850x; 1.1196x over previous
//
#include <hip/hip_runtime.h>
#include <hip/hip_bf16.h>
#include <math.h>

typedef unsigned long long u64;
typedef unsigned int u32;
typedef __hip_bfloat16 bf16;

#define N 1024
#define NCLS 21
#define APP 1024
#define DF 128
#define NH 16
#define DK 64

typedef __attribute__((ext_vector_type(8))) short short8v;
typedef __attribute__((ext_vector_type(4))) float float4v;
union U4S8 { uint4 u; short8v s; };

__device__ __forceinline__ float b2f(bf16 x) { return __bfloat162float(x); }
__device__ __forceinline__ ushort f2bu(float x) { bf16 b = __float2bfloat16(x); return *(ushort*)&b; }

// ---------------------------------------------------------------- k_prep
__global__ void k_prep(const float* __restrict__ roi, const float* __restrict__ cls_loc,
                       const float* __restrict__ score, const int* __restrict__ size,
                       float* __restrict__ prob, int* __restrict__ label,
                       float* __restrict__ bbox, u64* __restrict__ keys)
{
    int i = blockIdx.x * 256 + threadIdx.x;
    if (i >= N) return;
    float s[NCLS];
    float mx = -1e30f; int am = 0;
    for (int c = 0; c < NCLS; c++) {
        s[c] = score[i * NCLS + c];
        if (s[c] > mx) { mx = s[c]; am = c; }
    }
    float sum = 0.f;
    for (int c = 0; c < NCLS; c++) sum += expf(s[c] - mx);
    float p = 1.0f / sum;

    float y0 = roi[i*4+0], x0 = roi[i*4+1];
    float y1 = roi[i*4+2], x1 = roi[i*4+3];
    float hh = y1 - y0, ww = x1 - x0;
    float cy = y0 + 0.5f * hh, cx = x0 + 0.5f * ww;
    float l0 = cls_loc[i*84 + am*4 + 0] * 0.1f;
    float l1 = cls_loc[i*84 + am*4 + 1] * 0.1f;
    float l2 = cls_loc[i*84 + am*4 + 2] * 0.2f;
    float l3 = cls_loc[i*84 + am*4 + 3] * 0.2f;
    float ncy = l0 * hh + cy, ncx = l1 * ww + cx;
    float nh = expf(l2) * hh, nw = expf(l3) * ww;
    float b0 = ncy - 0.5f * nh, b1 = ncx - 0.5f * nw;
    float b2v = ncy + 0.5f * nh, b3 = ncx + 0.5f * nw;
    float lim = ((am & 1) == 0) ? (float)size[0] : (float)size[1];
    b0  = fminf(fmaxf(b0, 0.f), lim);
    b1  = fminf(fmaxf(b1, 0.f), lim);
    b2v = fminf(fmaxf(b2v, 0.f), lim);
    b3  = fminf(fmaxf(b3, 0.f), lim);
    prob[i] = p; label[i] = am;
    bbox[i*4+0] = b0; bbox[i*4+1] = b1; bbox[i*4+2] = b2v; bbox[i*4+3] = b3;
    keys[i] = ((u64)(0xFFFFFFFFu - __float_as_uint(p)) << 32) | (u32)i;
}

// ---------------------------------------------------------------- k_rank
// rank-by-counting (keys unique; low bits = index -> stable descending prob)
__global__ void __launch_bounds__(256) k_rank(
        const u64* __restrict__ keys, const float* __restrict__ prob,
        const int* __restrict__ label, const float* __restrict__ bbox,
        int* __restrict__ order, float* __restrict__ sprob,
        float* __restrict__ sbbox, float* __restrict__ out)
{
    __shared__ u64 sk[N];
    int t = threadIdx.x;
    int i = blockIdx.x * 256 + t;
    for (int j = t; j < N; j += 256) sk[j] = keys[j];
    __syncthreads();
    u64 my = sk[i];
    int r = 0;
    for (int j = 0; j < N; j++) r += (sk[j] < my) ? 1 : 0;
    order[r] = i;
    sprob[r] = prob[i];
    float b0 = bbox[i*4+0], b1 = bbox[i*4+1], b2 = bbox[i*4+2], b3 = bbox[i*4+3];
    sbbox[r*4+0] = b0; sbbox[r*4+1] = b1; sbbox[r*4+2] = b2; sbbox[r*4+3] = b3;
    out[N + r] = (float)(label[i] - 1);
    out[2*N + r*4 + 0] = b0;
    out[2*N + r*4 + 1] = b1;
    out[2*N + r*4 + 2] = b2;
    out[2*N + r*4 + 3] = b3;
}

// ---------------------------------------------------------------- k_emb2 (MFMA split-K)
// part[dc][row][col] = app[order[row], d0..d0+64] @ feat_w[d0.., col]
//                    + rank[row, d0..d0+64] @ rank_w[d0.., col]
__global__ void __launch_bounds__(256) k_emb2(
        const int* __restrict__ order, const float* __restrict__ app,
        const float* __restrict__ feat_w, const float* __restrict__ rank_w,
        float* __restrict__ part)
{
    __shared__ ushort sA[64][72];     // A bf16 [row][k], pitch 144B (16B aligned)
    __shared__ ushort sW[128][72];    // B bf16 [col][k]
    __shared__ int sOrd[64];
    int rt = blockIdx.x, dc = blockIdx.y, t = threadIdx.x;
    int r0 = rt * 64, d0 = dc * 64;
    int w = t >> 6, l = t & 63, l15 = l & 15, quad = l >> 4;
    if (t < 64) sOrd[t] = order[r0 + t];
    __syncthreads();

    float4v acc[8];
    #pragma unroll
    for (int nb = 0; nb < 8; nb++) acc[nb] = (float4v){0.f, 0.f, 0.f, 0.f};

    for (int phase = 0; phase < 2; phase++) {
        const float* Wsrc = phase ? rank_w : feat_w;
        #pragma unroll
        for (int it = 0; it < 32; it++) {        // W: 64x128
            int idx = t + it * 256;
            int d = idx >> 7, c = idx & 127;
            sW[c][d] = f2bu(Wsrc[(size_t)(d0 + d) * 128 + c]);
        }
        if (phase == 0) {
            #pragma unroll
            for (int it = 0; it < 16; it++) {    // A: 64x64 gathered rows
                int idx = t + it * 256;
                int r = idx >> 6, d = idx & 63;
                sA[r][d] = f2bu(app[(size_t)sOrd[r] * 1024 + d0 + d]);
            }
        } else {
            #pragma unroll
            for (int it = 0; it < 16; it++) {    // rank embedding analytic
                int idx = t + it * 256;
                int r = idx >> 6, d = idx & 63;
                int dgl = d0 + d;
                float irow = (float)(r0 + r);
                float val;
                if (dgl < 512) val = __sinf(irow * exp2f(-(float)dgl * 0.019464422f));
                else           val = __cosf(irow * exp2f(-(float)(dgl - 512) * 0.019464422f));
                sA[r][d] = f2bu(val);
            }
        }
        __syncthreads();
        U4S8 Af0, Af1;
        Af0.u = *(uint4*)&sA[w*16 + l15][quad*8];
        Af1.u = *(uint4*)&sA[w*16 + l15][32 + quad*8];
        #pragma unroll
        for (int nb = 0; nb < 8; nb++) {
            U4S8 Bf0, Bf1;
            Bf0.u = *(uint4*)&sW[nb*16 + l15][quad*8];
            Bf1.u = *(uint4*)&sW[nb*16 + l15][32 + quad*8];
            acc[nb] = __builtin_amdgcn_mfma_f32_16x16x32_bf16(Af0.s, Bf0.s, acc[nb], 0, 0, 0);
            acc[nb] = __builtin_amdgcn_mfma_f32_16x16x32_bf16(Af1.s, Bf1.s, acc[nb], 0, 0, 0);
        }
        __syncthreads();
    }
    #pragma unroll
    for (int reg = 0; reg < 4; reg++) {
        int row = r0 + w*16 + quad*4 + reg;
        #pragma unroll
        for (int nb = 0; nb < 8; nb++)
            part[((size_t)dc * 1024 + row) * 128 + nb*16 + l15] = acc[nb][reg];
    }
}

// ---------------------------------------------------------------- k_embsum (-> bf16)
__global__ void k_embsum(const float* __restrict__ part,
                         const float* __restrict__ feat_b, const float* __restrict__ rank_b,
                         bf16* __restrict__ embb)
{
    int gid = blockIdx.x * 256 + threadIdx.x;
    int c = gid & 127;
    float acc = feat_b[c] + rank_b[c];
    for (int dc = 0; dc < 16; dc++) acc += part[(size_t)dc * 131072 + gid];
    embb[gid] = __float2bfloat16(acc);
}

// ---------------------------------------------------------------- k_qkv2 (MFMA)
__global__ void __launch_bounds__(256) k_qkv2(
        const bf16* __restrict__ embb,
        const float* __restrict__ wq, const float* __restrict__ bq,
        const float* __restrict__ wk, const float* __restrict__ bk,
        const float* __restrict__ wv, const float* __restrict__ bv,
        bf16* __restrict__ q, bf16* __restrict__ k, bf16* __restrict__ v)
{
    __shared__ ushort sWt[64][136];
    int t = threadIdx.x;
    int rt = blockIdx.x, h = blockIdx.y, mat = blockIdx.z;
    const float* W  = (mat == 0) ? wq : (mat == 1) ? wk : wv;
    const float* Bb = (mat == 0) ? bq : (mat == 1) ? bk : bv;
    bf16* Out       = (mat == 0) ? q  : (mat == 1) ? k  : v;

    #pragma unroll
    for (int i = 0; i < 32; i++) {
        int idx = t + i * 256;
        int d = idx >> 6, kk = idx & 63;
        sWt[kk][d] = f2bu(W[((size_t)h * 128 + d) * 64 + kk]);
    }
    int w = t >> 6, l = t & 63, l15 = l & 15, quad = l >> 4;
    float biasv[4];
    #pragma unroll
    for (int nb = 0; nb < 4; nb++) biasv[nb] = Bb[h * 64 + nb*16 + l15];
    __syncthreads();

    U4S8 Bf[4][4];
    #pragma unroll
    for (int nb = 0; nb < 4; nb++)
        #pragma unroll
        for (int kc = 0; kc < 4; kc++)
            Bf[nb][kc].u = *(uint4*)&sWt[nb*16 + l15][kc*32 + quad*8];

    const uint4* A4 = (const uint4*)embb;
    int r0 = rt * 256 + w * 64;
    ushort* outu = (ushort*)Out;
    for (int mb = 0; mb < 4; mb++) {
        int arow = r0 + mb*16 + l15;
        U4S8 Af[4];
        #pragma unroll
        for (int kc = 0; kc < 4; kc++) Af[kc].u = A4[(size_t)arow * 16 + kc*4 + quad];
        float4v acc[4];
        #pragma unroll
        for (int nb = 0; nb < 4; nb++) acc[nb] = (float4v){0.f, 0.f, 0.f, 0.f};
        #pragma unroll
        for (int kc = 0; kc < 4; kc++)
            #pragma unroll
            for (int nb = 0; nb < 4; nb++)
                acc[nb] = __builtin_amdgcn_mfma_f32_16x16x32_bf16(Af[kc].s, Bf[nb][kc].s, acc[nb], 0, 0, 0);
        #pragma unroll
        for (int reg = 0; reg < 4; reg++) {
            int orow = r0 + mb*16 + quad*4 + reg;
            #pragma unroll
            for (int nb = 0; nb < 4; nb++)
                outu[((size_t)h * N + orow) * 64 + nb*16 + l15] = f2bu(acc[nb][reg] + biasv[nb]);
        }
    }
}

// ---------------------------------------------------------------- k_geo2 (MFMA head-projection)
// lw[h,m,n] = log(max(relu(posemb(m,n).wg_w[h] + wg_b[h]), 1e-6))
__global__ void __launch_bounds__(256) k_geo2(
        const float* __restrict__ sbbox, const float* __restrict__ wgw,
        const float* __restrict__ wgb, bf16* __restrict__ lw)
{
    __shared__ ushort sE[256][72];    // pair-emb bf16, pitch 144B
    __shared__ uint   sOut[NH][132];  // packed bf16 pairs, per head
    __shared__ float  mbb[4];
    int m = blockIdx.x, nc = blockIdx.y, t = threadIdx.x;
    int w = t >> 6, l = t & 63, l15 = l & 15, quad = l >> 4;

    if (t == 0) {
        float b0 = sbbox[m*4+0], b1 = sbbox[m*4+1], b2 = sbbox[m*4+2], b3 = sbbox[m*4+3];
        mbb[0] = (b0 + b2) * 0.5f; mbb[1] = (b1 + b3) * 0.5f;
        mbb[2] = b2 - b0 + 1.0f;   mbb[3] = b3 - b1 + 1.0f;
    }
    // B-fragment: head = l15, k = quad*8+j (chunk0), +32 (chunk1)
    U4S8 Bg0, Bg1;
    #pragma unroll
    for (int j = 0; j < 8; j++) {
        ((ushort*)&Bg0)[j] = f2bu(wgw[l15*64 + quad*8 + j]);
        ((ushort*)&Bg1)[j] = f2bu(wgw[l15*64 + 32 + quad*8 + j]);
    }
    float bias = wgb[l15];
    __syncthreads();

    int n = nc * 256 + t;
    float b0 = sbbox[n*4+0], b1 = sbbox[n*4+1], b2 = sbbox[n*4+2], b3 = sbbox[n*4+3];
    float cxn = (b0 + b2) * 0.5f, cyn = (b1 + b3) * 0.5f;
    float wn = b2 - b0 + 1.0f, hn = b3 - b1 + 1.0f;
    float dx = __logf(fmaxf(fabsf((mbb[0] - cxn) / mbb[2]), 1e-3f));
    float dy = __logf(fmaxf(fabsf((mbb[1] - cyn) / mbb[3]), 1e-3f));
    float dw = __logf(mbb[2] / wn);
    float dh = __logf(mbb[3] / hn);
    float pos[4] = { dx, dy, dw, dh };
    const float dmt[8] = { 1.0f, 0.42169650342f, 0.177827941f, 0.0749894209f,
                           0.0316227766f, 0.01333521432f, 0.00562341325f, 0.00237137371f };
    float args[32];
    #pragma unroll
    for (int c = 0; c < 4; c++)
        #pragma unroll
        for (int f = 0; f < 8; f++) args[c*8 + f] = 100.0f * pos[c] * dmt[f];
    uint* rowp = (uint*)&sE[t][0];
    #pragma unroll
    for (int jj = 0; jj < 16; jj++) {
        float s0 = __sinf(args[2*jj]), s1 = __sinf(args[2*jj+1]);
        rowp[jj] = (uint)f2bu(s0) | ((uint)f2bu(s1) << 16);
    }
    #pragma unroll
    for (int jj = 0; jj < 16; jj++) {
        float c0 = __cosf(args[2*jj]), c1 = __cosf(args[2*jj+1]);
        rowp[16 + jj] = (uint)f2bu(c0) | ((uint)f2bu(c1) << 16);
    }
    __syncthreads();

    // MFMA: wave w owns pairs w*64..w*64+63 (4 m-tiles of 16)
    #pragma unroll
    for (int mt2 = 0; mt2 < 4; mt2++) {
        int prow = w*64 + mt2*16 + l15;
        U4S8 Af0, Af1;
        Af0.u = *(uint4*)&sE[prow][quad*8];
        Af1.u = *(uint4*)&sE[prow][32 + quad*8];
        float4v c = (float4v){0.f, 0.f, 0.f, 0.f};
        c = __builtin_amdgcn_mfma_f32_16x16x32_bf16(Af0.s, Bg0.s, c, 0, 0, 0);
        c = __builtin_amdgcn_mfma_f32_16x16x32_bf16(Af1.s, Bg1.s, c, 0, 0, 0);
        float v0 = __logf(fmaxf(fmaxf(c[0] + bias, 0.f), 1e-6f));
        float v1 = __logf(fmaxf(fmaxf(c[1] + bias, 0.f), 1e-6f));
        float v2 = __logf(fmaxf(fmaxf(c[2] + bias, 0.f), 1e-6f));
        float v3 = __logf(fmaxf(fmaxf(c[3] + bias, 0.f), 1e-6f));
        int pb = (w*64 + mt2*16 + quad*4) >> 1;
        sOut[l15][pb]     = (uint)f2bu(v0) | ((uint)f2bu(v1) << 16);
        sOut[l15][pb + 1] = (uint)f2bu(v2) | ((uint)f2bu(v3) << 16);
    }
    __syncthreads();
    uint* lwu = (uint*)lw;
    #pragma unroll
    for (int it = 0; it < 8; it++) {
        int idx = t + it * 256;
        int hh = idx >> 7, col = idx & 127;
        lwu[((size_t)hh << 19) + ((size_t)m << 9) + nc*128 + col] = sOut[hh][col];
    }
}

// ---------------------------------------------------------------- k_attn3 (MFMA flash)
__global__ void __launch_bounds__(256) k_attn3(
        const bf16* __restrict__ q, const bf16* __restrict__ kmat,
        const bf16* __restrict__ v, const bf16* __restrict__ lw,
        bf16* __restrict__ rel)
{
    __shared__ uint sQu[64][36];
    __shared__ uint sVtu[64][36];
    __shared__ uint slwu[64][36];
    __shared__ uint sPu[4][16][36];

    int t = threadIdx.x;
    int mt = blockIdx.x, h = blockIdx.y;
    int m0 = mt * 64;
    int w = t >> 6, l = t & 63, l15 = l & 15, quad = l >> 4;

    U4S8 kf0, kf1;
    {
        const uint4* k4 = (const uint4*)kmat;
        size_t krow = ((size_t)h * N + m0 + w*16 + l15) * 8;
        kf0.u = k4[krow + quad];
        kf1.u = k4[krow + 4 + quad];
    }

    float4v O[4];
    float M[4], Z[4];
    #pragma unroll
    for (int i = 0; i < 4; i++) {
        O[i] = (float4v){0.f, 0.f, 0.f, 0.f};
        M[i] = -1e30f; Z[i] = 0.f;
    }

    const uint* qsrc = (const uint*)q;
    const uint* vsrc = (const uint*)v;
    const uint* lwsrc = (const uint*)lw;

    for (int tile = 0; tile < 16; tile++) {
        int n0 = tile * 64;
        #pragma unroll
        for (int i = 0; i < 8; i++) {
            int idx = t + i * 256;
            int nj = idx >> 5, kp = idx & 31;
            sQu[nj][kp] = qsrc[((size_t)h * N + n0 + nj) * 32 + kp];
        }
        #pragma unroll
        for (int i = 0; i < 4; i++) {
            int idx = t + i * 256;
            int a = idx & 31, nh2 = idx >> 5;
            uint g0 = vsrc[((size_t)h * N + n0 + 2*nh2) * 32 + a];
            uint g1 = vsrc[((size_t)h * N + n0 + 2*nh2 + 1) * 32 + a];
            sVtu[2*a][nh2]     = (g0 & 0xFFFFu) | (g1 << 16);
            sVtu[2*a + 1][nh2] = (g0 >> 16) | (g1 & 0xFFFF0000u);
        }
        #pragma unroll
        for (int i = 0; i < 8; i++) {
            int idx = t + i * 256;
            int mi = idx >> 5, np = idx & 31;
            slwu[mi][np] = lwsrc[((size_t)h << 19) + ((size_t)(m0 + mi) << 9) + (n0 >> 1) + np];
        }
        __syncthreads();

        float4v S[4];
        #pragma unroll
        for (int nb = 0; nb < 4; nb++) {
            U4S8 bq0, bq1;
            bq0.u = *(uint4*)&sQu[nb*16 + l15][quad*4];
            bq1.u = *(uint4*)&sQu[nb*16 + l15][16 + quad*4];
            float4v zz = (float4v){0.f, 0.f, 0.f, 0.f};
            float4v p0 = __builtin_amdgcn_mfma_f32_16x16x32_bf16(kf0.s, bq0.s, zz, 0, 0, 0);
            S[nb] = __builtin_amdgcn_mfma_f32_16x16x32_bf16(kf1.s, bq1.s, p0, 0, 0, 0);
        }
        ushort* pRow[4];
        #pragma unroll
        for (int r = 0; r < 4; r++) pRow[r] = (ushort*)&sPu[w][quad*4 + r][0];
        #pragma unroll
        for (int r = 0; r < 4; r++) {
            int mi = w*16 + quad*4 + r;
            float sv[4];
            #pragma unroll
            for (int nb = 0; nb < 4; nb++) {
                int col = nb*16 + l15;
                uint lu = slwu[mi][col >> 1];
                float lv = (col & 1) ? __uint_as_float(lu & 0xFFFF0000u)
                                     : __uint_as_float(lu << 16);
                sv[nb] = S[nb][r] * 0.125f + lv;
            }
            float rm = fmaxf(fmaxf(sv[0], sv[1]), fmaxf(sv[2], sv[3]));
            #pragma unroll
            for (int off = 1; off < 16; off <<= 1)
                rm = fmaxf(rm, __shfl_xor(rm, off, 64));
            float newM = fmaxf(M[r], rm);
            float pr[4], rs = 0.f;
            #pragma unroll
            for (int nb = 0; nb < 4; nb++) {
                pr[nb] = __expf(sv[nb] - newM);
                rs += pr[nb];
            }
            #pragma unroll
            for (int off = 1; off < 16; off <<= 1)
                rs += __shfl_xor(rs, off, 64);
            float sc = __expf(M[r] - newM);
            M[r] = newM;
            Z[r] = Z[r] * sc + rs;
            #pragma unroll
            for (int kvb = 0; kvb < 4; kvb++) O[kvb][r] *= sc;
            #pragma unroll
            for (int nb = 0; nb < 4; nb++)
                pRow[r][nb*16 + l15] = f2bu(pr[nb]);
        }
        {
            U4S8 ap0, ap1;
            ap0.u = *(uint4*)&sPu[w][l15][quad*4];
            ap1.u = *(uint4*)&sPu[w][l15][16 + quad*4];
            #pragma unroll
            for (int kvb = 0; kvb < 4; kvb++) {
                U4S8 bv0, bv1;
                bv0.u = *(uint4*)&sVtu[kvb*16 + l15][quad*4];
                bv1.u = *(uint4*)&sVtu[kvb*16 + l15][16 + quad*4];
                O[kvb] = __builtin_amdgcn_mfma_f32_16x16x32_bf16(ap0.s, bv0.s, O[kvb], 0, 0, 0);
                O[kvb] = __builtin_amdgcn_mfma_f32_16x16x32_bf16(ap1.s, bv1.s, O[kvb], 0, 0, 0);
            }
        }
        __syncthreads();
    }

    float invZ[4];
    #pragma unroll
    for (int r = 0; r < 4; r++) invZ[r] = 1.0f / Z[r];
    ushort* relu = (ushort*)rel;
    #pragma unroll
    for (int r = 0; r < 4; r++) {
        size_t mrow = ((size_t)h * N + m0 + w*16 + quad*4 + r) * 64;
        #pragma unroll
        for (int kvb = 0; kvb < 4; kvb++)
            relu[mrow + kvb*16 + l15] = f2bu(O[kvb][r] * invZ[r]);
    }
}

// ---------------------------------------------------------------- k_final
__global__ void k_final(const bf16* __restrict__ rel, const int* __restrict__ order,
                        const float* __restrict__ app, const float* __restrict__ lw,
                        const float* __restrict__ lb, const float* __restrict__ sprob,
                        float* __restrict__ out)
{
    __shared__ float red[2];
    int m = blockIdx.x, t = threadIdx.x;
    int o = order[m];
    float s = 0.f;
    for (int j = t; j < APP; j += 128) {
        int hh = j >> 6, kk = j & 63;
        float rv = b2f(rel[((size_t)hh * N + m) * DK + kk]) + app[o * APP + j];
        s += rv * lw[j];
    }
    #pragma unroll
    for (int off = 32; off > 0; off >>= 1) s += __shfl_down(s, off, 64);
    if ((t & 63) == 0) red[t >> 6] = s;
    __syncthreads();
    if (t == 0) {
        float tot = red[0] + red[1] + lb[0];
        float s1 = 1.0f / (1.0f + expf(-tot));
        out[m] = s1 * sprob[m];
    }
}

// ---------------------------------------------------------------- launch
extern "C" void kernel_launch(void* const* d_in, const int* in_sizes, int n_in,
                              void* d_out, int out_size, void* d_ws, size_t ws_size,
                              hipStream_t stream)
{
    const float* roi      = (const float*)d_in[0];
    const float* cls_loc  = (const float*)d_in[1];
    const float* score    = (const float*)d_in[2];
    const float* app      = (const float*)d_in[3];
    const int*   size     = (const int*)d_in[4];
    const float* rank_w   = (const float*)d_in[5];
    const float* rank_b   = (const float*)d_in[6];
    const float* feat_w   = (const float*)d_in[7];
    const float* feat_b   = (const float*)d_in[8];
    const float* logit_w  = (const float*)d_in[9];
    const float* logit_b  = (const float*)d_in[10];
    const float* wg_w     = (const float*)d_in[11];
    const float* wg_b     = (const float*)d_in[12];
    const float* wk_w     = (const float*)d_in[13];
    const float* wk_b     = (const float*)d_in[14];
    const float* wq_w     = (const float*)d_in[15];
    const float* wq_b     = (const float*)d_in[16];
    const float* wv_w     = (const float*)d_in[17];
    const float* wv_b     = (const float*)d_in[18];
    float* out = (float*)d_out;

    char* ws = (char*)d_ws;
    float* prob  = (float*)(ws + 0);
    int*   label = (int*)  (ws + 4096);
    float* bbox  = (float*)(ws + 8192);
    u64*   keys  = (u64*)  (ws + 24576);
    int*   order = (int*)  (ws + 32768);
    float* sprob = (float*)(ws + 36864);
    float* sbbox = (float*)(ws + 40960);
    bf16*  embb  = (bf16*) (ws + 57344);      // 256 KB
    float* part  = (float*)(ws + 581632);     // 8 MB
    bf16*  q     = (bf16*) (ws + 8970240);    // 2 MB
    bf16*  k     = (bf16*) (ws + 11067392);   // 2 MB
    bf16*  v     = (bf16*) (ws + 13164544);   // 2 MB
    bf16*  rel   = (bf16*) (ws + 15261696);   // 2 MB
    bf16*  lwbuf = (bf16*) (ws + 17358848);   // 32 MB

    k_prep<<<4, 256, 0, stream>>>(roi, cls_loc, score, size, prob, label, bbox, keys);
    k_rank<<<4, 256, 0, stream>>>(keys, prob, label, bbox, order, sprob, sbbox, out);
    k_emb2<<<dim3(16, 16), 256, 0, stream>>>(order, app, feat_w, rank_w, part);
    k_embsum<<<512, 256, 0, stream>>>(part, feat_b, rank_b, embb);
    k_qkv2<<<dim3(4, 16, 3), 256, 0, stream>>>(embb, wq_w, wq_b, wk_w, wk_b, wv_w, wv_b, q, k, v);
    k_geo2<<<dim3(1024, 4), 256, 0, stream>>>(sbbox, wg_w, wg_b, lwbuf);
    k_attn3<<<dim3(16, 16), 256, 0, stream>>>(q, k, v, lwbuf, rel);
    k_final<<<1024, 128, 0, stream>>>(rel, order, app, logit_w, logit_b, sprob, out);
}

// Round 9
// 190.543 us; speedup vs baseline: 3.5214x; 1.0104x over previous
//
#include <hip/hip_runtime.h>
#include <hip/hip_bf16.h>
#include <math.h>

typedef unsigned long long u64;
typedef unsigned int u32;
typedef __hip_bfloat16 bf16;

#define N 1024
#define NCLS 21
#define APP 1024
#define DF 128
#define NH 16
#define DK 64
#define NS 4     // n-splits in flash attention

typedef __attribute__((ext_vector_type(8))) short short8v;
typedef __attribute__((ext_vector_type(4))) float float4v;
union U4S8 { uint4 u; short8v s; };

__device__ __forceinline__ float b2f(bf16 x) { return __bfloat162float(x); }
__device__ __forceinline__ ushort f2bu(float x) { bf16 b = __float2bfloat16(x); return *(ushort*)&b; }

// ---------------------------------------------------------------- k_prep
__global__ void k_prep(const float* __restrict__ roi, const float* __restrict__ cls_loc,
                       const float* __restrict__ score, const int* __restrict__ size,
                       float* __restrict__ prob, int* __restrict__ label,
                       float* __restrict__ bbox, u64* __restrict__ keys)
{
    int i = blockIdx.x * 256 + threadIdx.x;
    if (i >= N) return;
    float s[NCLS];
    float mx = -1e30f; int am = 0;
    for (int c = 0; c < NCLS; c++) {
        s[c] = score[i * NCLS + c];
        if (s[c] > mx) { mx = s[c]; am = c; }
    }
    float sum = 0.f;
    for (int c = 0; c < NCLS; c++) sum += expf(s[c] - mx);
    float p = 1.0f / sum;

    float y0 = roi[i*4+0], x0 = roi[i*4+1];
    float y1 = roi[i*4+2], x1 = roi[i*4+3];
    float hh = y1 - y0, ww = x1 - x0;
    float cy = y0 + 0.5f * hh, cx = x0 + 0.5f * ww;
    float l0 = cls_loc[i*84 + am*4 + 0] * 0.1f;
    float l1 = cls_loc[i*84 + am*4 + 1] * 0.1f;
    float l2 = cls_loc[i*84 + am*4 + 2] * 0.2f;
    float l3 = cls_loc[i*84 + am*4 + 3] * 0.2f;
    float ncy = l0 * hh + cy, ncx = l1 * ww + cx;
    float nh = expf(l2) * hh, nw = expf(l3) * ww;
    float b0 = ncy - 0.5f * nh, b1 = ncx - 0.5f * nw;
    float b2v = ncy + 0.5f * nh, b3 = ncx + 0.5f * nw;
    float lim = ((am & 1) == 0) ? (float)size[0] : (float)size[1];
    b0  = fminf(fmaxf(b0, 0.f), lim);
    b1  = fminf(fmaxf(b1, 0.f), lim);
    b2v = fminf(fmaxf(b2v, 0.f), lim);
    b3  = fminf(fmaxf(b3, 0.f), lim);
    prob[i] = p; label[i] = am;
    bbox[i*4+0] = b0; bbox[i*4+1] = b1; bbox[i*4+2] = b2v; bbox[i*4+3] = b3;
    keys[i] = ((u64)(0xFFFFFFFFu - __float_as_uint(p)) << 32) | (u32)i;
}

// ---------------------------------------------------------------- k_rank
__global__ void __launch_bounds__(256) k_rank(
        const u64* __restrict__ keys, const float* __restrict__ prob,
        const int* __restrict__ label, const float* __restrict__ bbox,
        int* __restrict__ order, float* __restrict__ sprob,
        float* __restrict__ sbbox, float* __restrict__ out)
{
    __shared__ u64 sk[N];
    int t = threadIdx.x;
    int i = blockIdx.x * 256 + t;
    for (int j = t; j < N; j += 256) sk[j] = keys[j];
    __syncthreads();
    u64 my = sk[i];
    int r = 0;
    for (int j = 0; j < N; j++) r += (sk[j] < my) ? 1 : 0;
    order[r] = i;
    sprob[r] = prob[i];
    float b0 = bbox[i*4+0], b1 = bbox[i*4+1], b2 = bbox[i*4+2], b3 = bbox[i*4+3];
    sbbox[r*4+0] = b0; sbbox[r*4+1] = b1; sbbox[r*4+2] = b2; sbbox[r*4+3] = b3;
    out[N + r] = (float)(label[i] - 1);
    out[2*N + r*4 + 0] = b0;
    out[2*N + r*4 + 1] = b1;
    out[2*N + r*4 + 2] = b2;
    out[2*N + r*4 + 3] = b3;
}

// ---------------------------------------------------------------- k_emb3 (MFMA, phase-split)
// part[ph][dc][row][col]; ph0: app@feat_w, ph1: rank@rank_w
__global__ void __launch_bounds__(256) k_emb3(
        const int* __restrict__ order, const float* __restrict__ app,
        const float* __restrict__ feat_w, const float* __restrict__ rank_w,
        float* __restrict__ part)
{
    __shared__ ushort sA[64][72];
    __shared__ ushort sW[128][72];
    __shared__ int sOrd[64];
    int rt = blockIdx.x, dc = blockIdx.y, ph = blockIdx.z, t = threadIdx.x;
    int r0 = rt * 64, d0 = dc * 64;
    int w = t >> 6, l = t & 63, l15 = l & 15, quad = l >> 4;
    if (t < 64) sOrd[t] = order[r0 + t];
    __syncthreads();

    const float* Wsrc = ph ? rank_w : feat_w;
    #pragma unroll
    for (int it = 0; it < 32; it++) {
        int idx = t + it * 256;
        int d = idx >> 7, c = idx & 127;
        sW[c][d] = f2bu(Wsrc[(size_t)(d0 + d) * 128 + c]);
    }
    if (ph == 0) {
        #pragma unroll
        for (int it = 0; it < 16; it++) {
            int idx = t + it * 256;
            int r = idx >> 6, d = idx & 63;
            sA[r][d] = f2bu(app[(size_t)sOrd[r] * 1024 + d0 + d]);
        }
    } else {
        #pragma unroll
        for (int it = 0; it < 16; it++) {
            int idx = t + it * 256;
            int r = idx >> 6, d = idx & 63;
            int dgl = d0 + d;
            float irow = (float)(r0 + r);
            float val;
            if (dgl < 512) val = __sinf(irow * exp2f(-(float)dgl * 0.019464422f));
            else           val = __cosf(irow * exp2f(-(float)(dgl - 512) * 0.019464422f));
            sA[r][d] = f2bu(val);
        }
    }
    __syncthreads();

    U4S8 Af0, Af1;
    Af0.u = *(uint4*)&sA[w*16 + l15][quad*8];
    Af1.u = *(uint4*)&sA[w*16 + l15][32 + quad*8];
    float4v acc[8];
    #pragma unroll
    for (int nb = 0; nb < 8; nb++) acc[nb] = (float4v){0.f, 0.f, 0.f, 0.f};
    #pragma unroll
    for (int nb = 0; nb < 8; nb++) {
        U4S8 Bf0, Bf1;
        Bf0.u = *(uint4*)&sW[nb*16 + l15][quad*8];
        Bf1.u = *(uint4*)&sW[nb*16 + l15][32 + quad*8];
        acc[nb] = __builtin_amdgcn_mfma_f32_16x16x32_bf16(Af0.s, Bf0.s, acc[nb], 0, 0, 0);
        acc[nb] = __builtin_amdgcn_mfma_f32_16x16x32_bf16(Af1.s, Bf1.s, acc[nb], 0, 0, 0);
    }
    #pragma unroll
    for (int reg = 0; reg < 4; reg++) {
        int row = r0 + w*16 + quad*4 + reg;
        #pragma unroll
        for (int nb = 0; nb < 8; nb++)
            part[(((size_t)ph * 16 + dc) * 1024 + row) * 128 + nb*16 + l15] = acc[nb][reg];
    }
}

// ---------------------------------------------------------------- k_embsum (-> bf16)
__global__ void k_embsum(const float* __restrict__ part,
                         const float* __restrict__ feat_b, const float* __restrict__ rank_b,
                         bf16* __restrict__ embb)
{
    int gid = blockIdx.x * 256 + threadIdx.x;
    int c = gid & 127;
    float acc = feat_b[c] + rank_b[c];
    for (int dc = 0; dc < 32; dc++) acc += part[(size_t)dc * 131072 + gid];
    embb[gid] = __float2bfloat16(acc);
}

// ---------------------------------------------------------------- k_qkv2 (MFMA)
__global__ void __launch_bounds__(256) k_qkv2(
        const bf16* __restrict__ embb,
        const float* __restrict__ wq, const float* __restrict__ bq,
        const float* __restrict__ wk, const float* __restrict__ bk,
        const float* __restrict__ wv, const float* __restrict__ bv,
        bf16* __restrict__ q, bf16* __restrict__ k, bf16* __restrict__ v)
{
    __shared__ ushort sWt[64][136];
    int t = threadIdx.x;
    int rt = blockIdx.x, h = blockIdx.y, mat = blockIdx.z;
    const float* W  = (mat == 0) ? wq : (mat == 1) ? wk : wv;
    const float* Bb = (mat == 0) ? bq : (mat == 1) ? bk : bv;
    bf16* Out       = (mat == 0) ? q  : (mat == 1) ? k  : v;

    #pragma unroll
    for (int i = 0; i < 32; i++) {
        int idx = t + i * 256;
        int d = idx >> 6, kk = idx & 63;
        sWt[kk][d] = f2bu(W[((size_t)h * 128 + d) * 64 + kk]);
    }
    int w = t >> 6, l = t & 63, l15 = l & 15, quad = l >> 4;
    float biasv[4];
    #pragma unroll
    for (int nb = 0; nb < 4; nb++) biasv[nb] = Bb[h * 64 + nb*16 + l15];
    __syncthreads();

    U4S8 Bf[4][4];
    #pragma unroll
    for (int nb = 0; nb < 4; nb++)
        #pragma unroll
        for (int kc = 0; kc < 4; kc++)
            Bf[nb][kc].u = *(uint4*)&sWt[nb*16 + l15][kc*32 + quad*8];

    const uint4* A4 = (const uint4*)embb;
    int r0 = rt * 128 + w * 32;
    ushort* outu = (ushort*)Out;
    for (int mb = 0; mb < 2; mb++) {
        int arow = r0 + mb*16 + l15;
        U4S8 Af[4];
        #pragma unroll
        for (int kc = 0; kc < 4; kc++) Af[kc].u = A4[(size_t)arow * 16 + kc*4 + quad];
        float4v acc[4];
        #pragma unroll
        for (int nb = 0; nb < 4; nb++) acc[nb] = (float4v){0.f, 0.f, 0.f, 0.f};
        #pragma unroll
        for (int kc = 0; kc < 4; kc++)
            #pragma unroll
            for (int nb = 0; nb < 4; nb++)
                acc[nb] = __builtin_amdgcn_mfma_f32_16x16x32_bf16(Af[kc].s, Bf[nb][kc].s, acc[nb], 0, 0, 0);
        #pragma unroll
        for (int reg = 0; reg < 4; reg++) {
            int orow = r0 + mb*16 + quad*4 + reg;
            #pragma unroll
            for (int nb = 0; nb < 4; nb++)
                outu[((size_t)h * N + orow) * 64 + nb*16 + l15] = f2bu(acc[nb][reg] + biasv[nb]);
        }
    }
}

// ---------------------------------------------------------------- k_geo2 (MFMA head-projection)
__global__ void __launch_bounds__(256) k_geo2(
        const float* __restrict__ sbbox, const float* __restrict__ wgw,
        const float* __restrict__ wgb, bf16* __restrict__ lw)
{
    __shared__ ushort sE[256][72];
    __shared__ uint   sOut[NH][132];
    __shared__ float  mbb[4];
    int m = blockIdx.x, nc = blockIdx.y, t = threadIdx.x;
    int w = t >> 6, l = t & 63, l15 = l & 15, quad = l >> 4;

    if (t == 0) {
        float b0 = sbbox[m*4+0], b1 = sbbox[m*4+1], b2 = sbbox[m*4+2], b3 = sbbox[m*4+3];
        mbb[0] = (b0 + b2) * 0.5f; mbb[1] = (b1 + b3) * 0.5f;
        mbb[2] = b2 - b0 + 1.0f;   mbb[3] = b3 - b1 + 1.0f;
    }
    U4S8 Bg0, Bg1;
    #pragma unroll
    for (int j = 0; j < 8; j++) {
        ((ushort*)&Bg0)[j] = f2bu(wgw[l15*64 + quad*8 + j]);
        ((ushort*)&Bg1)[j] = f2bu(wgw[l15*64 + 32 + quad*8 + j]);
    }
    float bias = wgb[l15];
    __syncthreads();

    int n = nc * 256 + t;
    float b0 = sbbox[n*4+0], b1 = sbbox[n*4+1], b2 = sbbox[n*4+2], b3 = sbbox[n*4+3];
    float cxn = (b0 + b2) * 0.5f, cyn = (b1 + b3) * 0.5f;
    float wn = b2 - b0 + 1.0f, hn = b3 - b1 + 1.0f;
    float dx = __logf(fmaxf(fabsf((mbb[0] - cxn) / mbb[2]), 1e-3f));
    float dy = __logf(fmaxf(fabsf((mbb[1] - cyn) / mbb[3]), 1e-3f));
    float dw = __logf(mbb[2] / wn);
    float dh = __logf(mbb[3] / hn);
    float pos[4] = { dx, dy, dw, dh };
    const float dmt[8] = { 1.0f, 0.42169650342f, 0.177827941f, 0.0749894209f,
                           0.0316227766f, 0.01333521432f, 0.00562341325f, 0.00237137371f };
    float args[32];
    #pragma unroll
    for (int c = 0; c < 4; c++)
        #pragma unroll
        for (int f = 0; f < 8; f++) args[c*8 + f] = 100.0f * pos[c] * dmt[f];
    uint* rowp = (uint*)&sE[t][0];
    #pragma unroll
    for (int jj = 0; jj < 16; jj++) {
        float s0 = __sinf(args[2*jj]), s1 = __sinf(args[2*jj+1]);
        rowp[jj] = (uint)f2bu(s0) | ((uint)f2bu(s1) << 16);
    }
    #pragma unroll
    for (int jj = 0; jj < 16; jj++) {
        float c0 = __cosf(args[2*jj]), c1 = __cosf(args[2*jj+1]);
        rowp[16 + jj] = (uint)f2bu(c0) | ((uint)f2bu(c1) << 16);
    }
    __syncthreads();

    #pragma unroll
    for (int mt2 = 0; mt2 < 4; mt2++) {
        int prow = w*64 + mt2*16 + l15;
        U4S8 Af0, Af1;
        Af0.u = *(uint4*)&sE[prow][quad*8];
        Af1.u = *(uint4*)&sE[prow][32 + quad*8];
        float4v c = (float4v){0.f, 0.f, 0.f, 0.f};
        c = __builtin_amdgcn_mfma_f32_16x16x32_bf16(Af0.s, Bg0.s, c, 0, 0, 0);
        c = __builtin_amdgcn_mfma_f32_16x16x32_bf16(Af1.s, Bg1.s, c, 0, 0, 0);
        float v0 = __logf(fmaxf(fmaxf(c[0] + bias, 0.f), 1e-6f));
        float v1 = __logf(fmaxf(fmaxf(c[1] + bias, 0.f), 1e-6f));
        float v2 = __logf(fmaxf(fmaxf(c[2] + bias, 0.f), 1e-6f));
        float v3 = __logf(fmaxf(fmaxf(c[3] + bias, 0.f), 1e-6f));
        int pb = (w*64 + mt2*16 + quad*4) >> 1;
        sOut[l15][pb]     = (uint)f2bu(v0) | ((uint)f2bu(v1) << 16);
        sOut[l15][pb + 1] = (uint)f2bu(v2) | ((uint)f2bu(v3) << 16);
    }
    __syncthreads();
    uint* lwu = (uint*)lw;
    #pragma unroll
    for (int it = 0; it < 8; it++) {
        int idx = t + it * 256;
        int hh = idx >> 7, col = idx & 127;
        lwu[((size_t)hh << 19) + ((size_t)m << 9) + nc*128 + col] = sOut[hh][col];
    }
}

// ---------------------------------------------------------------- k_attn4 (MFMA flash, n-split)
__global__ void __launch_bounds__(256) k_attn4(
        const bf16* __restrict__ q, const bf16* __restrict__ kmat,
        const bf16* __restrict__ v, const bf16* __restrict__ lw,
        float* __restrict__ opart, float* __restrict__ mpart, float* __restrict__ zpart)
{
    __shared__ uint sQu[64][36];
    __shared__ uint sVtu[64][36];
    __shared__ uint slwu[64][36];
    __shared__ uint sPu[4][16][36];

    int t = threadIdx.x;
    int mt = blockIdx.x, h = blockIdx.y, ns = blockIdx.z;
    int m0 = mt * 64;
    int w = t >> 6, l = t & 63, l15 = l & 15, quad = l >> 4;

    U4S8 kf0, kf1;
    {
        const uint4* k4 = (const uint4*)kmat;
        size_t krow = ((size_t)h * N + m0 + w*16 + l15) * 8;
        kf0.u = k4[krow + quad];
        kf1.u = k4[krow + 4 + quad];
    }

    float4v O[4];
    float M[4], Z[4];
    #pragma unroll
    for (int i = 0; i < 4; i++) {
        O[i] = (float4v){0.f, 0.f, 0.f, 0.f};
        M[i] = -1e30f; Z[i] = 0.f;
    }

    const uint* qsrc = (const uint*)q;
    const uint* vsrc = (const uint*)v;
    const uint* lwsrc = (const uint*)lw;

    for (int tile = ns * (16/NS); tile < (ns + 1) * (16/NS); tile++) {
        int n0 = tile * 64;
        #pragma unroll
        for (int i = 0; i < 8; i++) {
            int idx = t + i * 256;
            int nj = idx >> 5, kp = idx & 31;
            sQu[nj][kp] = qsrc[((size_t)h * N + n0 + nj) * 32 + kp];
        }
        #pragma unroll
        for (int i = 0; i < 4; i++) {
            int idx = t + i * 256;
            int a = idx & 31, nh2 = idx >> 5;
            uint g0 = vsrc[((size_t)h * N + n0 + 2*nh2) * 32 + a];
            uint g1 = vsrc[((size_t)h * N + n0 + 2*nh2 + 1) * 32 + a];
            sVtu[2*a][nh2]     = (g0 & 0xFFFFu) | (g1 << 16);
            sVtu[2*a + 1][nh2] = (g0 >> 16) | (g1 & 0xFFFF0000u);
        }
        #pragma unroll
        for (int i = 0; i < 8; i++) {
            int idx = t + i * 256;
            int mi = idx >> 5, np = idx & 31;
            slwu[mi][np] = lwsrc[((size_t)h << 19) + ((size_t)(m0 + mi) << 9) + (n0 >> 1) + np];
        }
        __syncthreads();

        float4v S[4];
        #pragma unroll
        for (int nb = 0; nb < 4; nb++) {
            U4S8 bq0, bq1;
            bq0.u = *(uint4*)&sQu[nb*16 + l15][quad*4];
            bq1.u = *(uint4*)&sQu[nb*16 + l15][16 + quad*4];
            float4v zz = (float4v){0.f, 0.f, 0.f, 0.f};
            float4v p0 = __builtin_amdgcn_mfma_f32_16x16x32_bf16(kf0.s, bq0.s, zz, 0, 0, 0);
            S[nb] = __builtin_amdgcn_mfma_f32_16x16x32_bf16(kf1.s, bq1.s, p0, 0, 0, 0);
        }
        ushort* pRow[4];
        #pragma unroll
        for (int r = 0; r < 4; r++) pRow[r] = (ushort*)&sPu[w][quad*4 + r][0];
        #pragma unroll
        for (int r = 0; r < 4; r++) {
            int mi = w*16 + quad*4 + r;
            float sv[4];
            #pragma unroll
            for (int nb = 0; nb < 4; nb++) {
                int col = nb*16 + l15;
                uint lu = slwu[mi][col >> 1];
                float lv = (col & 1) ? __uint_as_float(lu & 0xFFFF0000u)
                                     : __uint_as_float(lu << 16);
                sv[nb] = S[nb][r] * 0.125f + lv;
            }
            float rm = fmaxf(fmaxf(sv[0], sv[1]), fmaxf(sv[2], sv[3]));
            #pragma unroll
            for (int off = 1; off < 16; off <<= 1)
                rm = fmaxf(rm, __shfl_xor(rm, off, 64));
            float newM = fmaxf(M[r], rm);
            float pr[4], rs = 0.f;
            #pragma unroll
            for (int nb = 0; nb < 4; nb++) {
                pr[nb] = __expf(sv[nb] - newM);
                rs += pr[nb];
            }
            #pragma unroll
            for (int off = 1; off < 16; off <<= 1)
                rs += __shfl_xor(rs, off, 64);
            float sc = __expf(M[r] - newM);
            M[r] = newM;
            Z[r] = Z[r] * sc + rs;
            #pragma unroll
            for (int kvb = 0; kvb < 4; kvb++) O[kvb][r] *= sc;
            #pragma unroll
            for (int nb = 0; nb < 4; nb++)
                pRow[r][nb*16 + l15] = f2bu(pr[nb]);
        }
        {
            U4S8 ap0, ap1;
            ap0.u = *(uint4*)&sPu[w][l15][quad*4];
            ap1.u = *(uint4*)&sPu[w][l15][16 + quad*4];
            #pragma unroll
            for (int kvb = 0; kvb < 4; kvb++) {
                U4S8 bv0, bv1;
                bv0.u = *(uint4*)&sVtu[kvb*16 + l15][quad*4];
                bv1.u = *(uint4*)&sVtu[kvb*16 + l15][16 + quad*4];
                O[kvb] = __builtin_amdgcn_mfma_f32_16x16x32_bf16(ap0.s, bv0.s, O[kvb], 0, 0, 0);
                O[kvb] = __builtin_amdgcn_mfma_f32_16x16x32_bf16(ap1.s, bv1.s, O[kvb], 0, 0, 0);
            }
        }
        __syncthreads();
    }

    // epilogue: write unnormalized partials (O, M, Z)
    #pragma unroll
    for (int r = 0; r < 4; r++) {
        int m = m0 + w*16 + quad*4 + r;
        size_t row = ((size_t)ns * NH + h) * N + m;
        #pragma unroll
        for (int kvb = 0; kvb < 4; kvb++)
            opart[row * 64 + kvb*16 + l15] = O[kvb][r];
        if (l15 == 0) { mpart[row] = M[r]; zpart[row] = Z[r]; }
    }
}

// ---------------------------------------------------------------- k_amerge
// rel[h,m,:] = (sum_ns O_ns * e^{M_ns-Mg}) / (sum_ns Z_ns * e^{M_ns-Mg})
__global__ void __launch_bounds__(256) k_amerge(
        const float* __restrict__ opart, const float* __restrict__ mpart,
        const float* __restrict__ zpart, bf16* __restrict__ rel)
{
    int gid = blockIdx.x * 256 + threadIdx.x;   // 0..262143
    int row = gid >> 4;                          // h*N + m, 0..16383
    int colq = gid & 15;
    float Ms[NS];
    float Mg = -1e30f;
    #pragma unroll
    for (int ns = 0; ns < NS; ns++) {
        Ms[ns] = mpart[(size_t)ns * 16384 + row];
        Mg = fmaxf(Mg, Ms[ns]);
    }
    float Zt = 0.f;
    float acc0 = 0.f, acc1 = 0.f, acc2 = 0.f, acc3 = 0.f;
    #pragma unroll
    for (int ns = 0; ns < NS; ns++) {
        float wgt = __expf(Ms[ns] - Mg);
        Zt += zpart[(size_t)ns * 16384 + row] * wgt;
        float4 o = *(const float4*)&opart[((size_t)ns * 16384 + row) * 64 + colq*4];
        acc0 += o.x * wgt; acc1 += o.y * wgt; acc2 += o.z * wgt; acc3 += o.w * wgt;
    }
    float inv = 1.0f / Zt;
    ushort* relu = (ushort*)rel;
    size_t base = (size_t)row * 64 + colq*4;
    relu[base + 0] = f2bu(acc0 * inv);
    relu[base + 1] = f2bu(acc1 * inv);
    relu[base + 2] = f2bu(acc2 * inv);
    relu[base + 3] = f2bu(acc3 * inv);
}

// ---------------------------------------------------------------- k_final
__global__ void k_final(const bf16* __restrict__ rel, const int* __restrict__ order,
                        const float* __restrict__ app, const float* __restrict__ lw,
                        const float* __restrict__ lb, const float* __restrict__ sprob,
                        float* __restrict__ out)
{
    __shared__ float red[2];
    int m = blockIdx.x, t = threadIdx.x;
    int o = order[m];
    float s = 0.f;
    for (int j = t; j < APP; j += 128) {
        int hh = j >> 6, kk = j & 63;
        float rv = b2f(rel[((size_t)hh * N + m) * DK + kk]) + app[o * APP + j];
        s += rv * lw[j];
    }
    #pragma unroll
    for (int off = 32; off > 0; off >>= 1) s += __shfl_down(s, off, 64);
    if ((t & 63) == 0) red[t >> 6] = s;
    __syncthreads();
    if (t == 0) {
        float tot = red[0] + red[1] + lb[0];
        float s1 = 1.0f / (1.0f + expf(-tot));
        out[m] = s1 * sprob[m];
    }
}

// ---------------------------------------------------------------- launch
extern "C" void kernel_launch(void* const* d_in, const int* in_sizes, int n_in,
                              void* d_out, int out_size, void* d_ws, size_t ws_size,
                              hipStream_t stream)
{
    const float* roi      = (const float*)d_in[0];
    const float* cls_loc  = (const float*)d_in[1];
    const float* score    = (const float*)d_in[2];
    const float* app      = (const float*)d_in[3];
    const int*   size     = (const int*)d_in[4];
    const float* rank_w   = (const float*)d_in[5];
    const float* rank_b   = (const float*)d_in[6];
    const float* feat_w   = (const float*)d_in[7];
    const float* feat_b   = (const float*)d_in[8];
    const float* logit_w  = (const float*)d_in[9];
    const float* logit_b  = (const float*)d_in[10];
    const float* wg_w     = (const float*)d_in[11];
    const float* wg_b     = (const float*)d_in[12];
    const float* wk_w     = (const float*)d_in[13];
    const float* wk_b     = (const float*)d_in[14];
    const float* wq_w     = (const float*)d_in[15];
    const float* wq_b     = (const float*)d_in[16];
    const float* wv_w     = (const float*)d_in[17];
    const float* wv_b     = (const float*)d_in[18];
    float* out = (float*)d_out;

    // ws_size = 256 MiB (confirmed via fillBuffer WRITE_SIZE); using ~85 MB
    char* ws = (char*)d_ws;
    float* prob  = (float*)(ws + 0);
    int*   label = (int*)  (ws + 4096);
    float* bbox  = (float*)(ws + 8192);
    u64*   keys  = (u64*)  (ws + 24576);
    int*   order = (int*)  (ws + 32768);
    float* sprob = (float*)(ws + 36864);
    float* sbbox = (float*)(ws + 40960);
    bf16*  embb  = (bf16*) (ws + 57344);      // 256 KB
    bf16*  q     = (bf16*) (ws + 8970240);    // 2 MB
    bf16*  k     = (bf16*) (ws + 11067392);   // 2 MB
    bf16*  v     = (bf16*) (ws + 13164544);   // 2 MB
    bf16*  rel   = (bf16*) (ws + 15261696);   // 2 MB
    bf16*  lwbuf = (bf16*) (ws + 17358848);   // 32 MB
    float* part  = (float*)(ws + 50913280);   // 16 MB  [2][16][1024][128]
    float* opart = (float*)(ws + 67690496);   // 16 MB  [NS][16][1024][64]
    float* mpart = (float*)(ws + 84467712);   // 256 KB [NS][16][1024]
    float* zpart = (float*)(ws + 84729856);   // 256 KB

    k_prep<<<4, 256, 0, stream>>>(roi, cls_loc, score, size, prob, label, bbox, keys);
    k_rank<<<4, 256, 0, stream>>>(keys, prob, label, bbox, order, sprob, sbbox, out);
    k_emb3<<<dim3(16, 16, 2), 256, 0, stream>>>(order, app, feat_w, rank_w, part);
    k_embsum<<<512, 256, 0, stream>>>(part, feat_b, rank_b, embb);
    k_qkv2<<<dim3(8, 16, 3), 256, 0, stream>>>(embb, wq_w, wq_b, wk_w, wk_b, wv_w, wv_b, q, k, v);
    k_geo2<<<dim3(1024, 4), 256, 0, stream>>>(sbbox, wg_w, wg_b, lwbuf);
    k_attn4<<<dim3(16, 16, NS), 256, 0, stream>>>(q, k, v, lwbuf, opart, mpart, zpart);
    k_amerge<<<1024, 256, 0, stream>>>(opart, mpart, zpart, rel);
    k_final<<<1024, 128, 0, stream>>>(rel, order, app, logit_w, logit_b, sprob, out);
}